// Round 13
// baseline (577.844 us; speedup 1.0000x reference)
//
#include <hip/hip_runtime.h>
#include <math.h>

#define DEV __device__ __forceinline__

typedef __bf16 bf16x8 __attribute__((ext_vector_type(8)));
typedef float f32x4 __attribute__((ext_vector_type(4)));
typedef unsigned short u16x8 __attribute__((ext_vector_type(8)));

typedef const __attribute__((address_space(1))) void gv_t;
typedef __attribute__((address_space(3))) void lv_t;

DEV unsigned short f2bf(float f){
  unsigned int u = __float_as_uint(f);
  u += 0x7fffu + ((u >> 16) & 1u);     // round-to-nearest-even
  return (unsigned short)(u >> 16);
}
DEV float bf2f(unsigned short u){ return __uint_as_float((unsigned)u << 16); }

DEV void gload16(const void* g, void* l){
  __builtin_amdgcn_global_load_lds((gv_t*)g, (lv_t*)l, 16, 0, 0);
}

// T1 chunked XCD swizzle (bijective when nwg%8==0, identity otherwise).
DEV void xcd_decode(int& bx, int& by, int& bz){
  const int gx = gridDim.x, gy = gridDim.y;
  const int nwg = gx * gy * gridDim.z;
  int lin = blockIdx.x + gx*(blockIdx.y + gy*blockIdx.z);
  if ((nwg & 7) == 0) lin = (lin & 7)*(nwg >> 3) + (lin >> 3);
  bx = lin % gx; const int t = lin / gx;
  by = t % gy;  bz = t / gy;
}

// ---------------------------------------------------------------------------
// gemm256: 256x256 tile, BK=64, 8 waves, 2-phase dbuf, XOR swizzle.
// CMODE: 0=f32 store, 1=bf16 store, 2=bf16 gelu store.
// CSK: 0 none, 1 causal block-skip, 2 causal K-clamp.
// Batched over bz (z = b*8+h or k-slice).
// ---------------------------------------------------------------------------
template<int CMODE, int CSK>
__global__ __launch_bounds__(512, 2)
void gemm256(const unsigned short* __restrict__ A, const unsigned short* __restrict__ B,
             void* __restrict__ C, const float* __restrict__ bias,
             int M, int N, int K, int lda, int ldb, int ldc,
             size_t aOffH, size_t aOffB, size_t bOffH, size_t bOffB,
             size_t cOffH, size_t cOffB)
{
  __shared__ unsigned short Ab[2][16384];
  __shared__ unsigned short Bb[2][16384];

  int bxi, byi, bzi; xcd_decode(bxi, byi, bzi);
  const int m0 = byi*256, n0 = bxi*256;
  if (CSK == 1 && n0 > m0 + 255) return;     // fully-masked causal block

  const int z = bzi, bb = z >> 3, hh = z & 7;
  A += (size_t)bb*aOffB + (size_t)hh*aOffH;
  B += (size_t)bb*bOffB + (size_t)hh*bOffH;
  const size_t coff = (size_t)bb*cOffB + (size_t)hh*cOffH;

  const int tid = threadIdx.x, lane = tid & 63, w = tid >> 6;
  const int wr = w >> 2, wc = w & 3;
  const int l15 = lane & 15, l4 = lane >> 4;

  int Keff = K;
  if (CSK == 2) Keff = (m0 + 256 < K) ? (m0 + 256) : K;
  const int nt = Keff >> 6;

  const int r8  = tid >> 3;
  const int sc8 = ((tid & 7) ^ (r8 & 7)) * 8;

  auto stage = [&](int buf, int kt){
    #pragma unroll
    for (int j = 0; j < 4; j++){
      gload16(A + (size_t)(m0 + j*64 + r8)*lda + kt + sc8, &Ab[buf][j*4096 + tid*8]);
      gload16(B + (size_t)(n0 + j*64 + r8)*ldb + kt + sc8, &Bb[buf][j*4096 + tid*8]);
    }
  };

  f32x4 acc[8][4] = {};

  stage(0, 0);
  __syncthreads();
  for (int t = 0; t < nt; t++){
    const int cur = t & 1;
    if (t + 1 < nt) stage(cur ^ 1, (t+1)*64);

    bf16x8 bfr[4][2];
    #pragma unroll
    for (int fc = 0; fc < 4; fc++){
      const int R = wc*64 + fc*16 + l15;
      #pragma unroll
      for (int kc = 0; kc < 2; kc++){
        const int cc = (kc*32 + l4*8) ^ ((R & 7) * 8);
        bfr[fc][kc] = *(const bf16x8*)&Bb[cur][R*64 + cc];
      }
    }
    #pragma unroll
    for (int fr = 0; fr < 8; fr++){
      bf16x8 ar[2];
      const int R = wr*128 + fr*16 + l15;
      #pragma unroll
      for (int kc = 0; kc < 2; kc++){
        const int cc = (kc*32 + l4*8) ^ ((R & 7) * 8);
        ar[kc] = *(const bf16x8*)&Ab[cur][R*64 + cc];
      }
      #pragma unroll
      for (int fc = 0; fc < 4; fc++)
        #pragma unroll
        for (int kc = 0; kc < 2; kc++)
          acc[fr][fc] = __builtin_amdgcn_mfma_f32_16x16x32_bf16(
              ar[kc], bfr[fc][kc], acc[fr][fc], 0, 0, 0);
    }
    __syncthreads();
  }

  #pragma unroll
  for (int fr = 0; fr < 8; fr++){
    const int mb = m0 + wr*128 + fr*16 + l4*4;
    #pragma unroll
    for (int fc = 0; fc < 4; fc++){
      const int n = n0 + wc*64 + fc*16 + l15;
      const float bv = bias ? bias[n] : 0.0f;
      #pragma unroll
      for (int r = 0; r < 4; r++){
        float v = acc[fr][fc][r] + bv;
        if (CMODE == 0){
          ((float*)C)[coff + (size_t)(mb + r)*ldc + n] = v;
        } else if (CMODE == 1){
          ((unsigned short*)C)[coff + (size_t)(mb + r)*ldc + n] = f2bf(v);
        } else {
          v = 0.5f * v * (1.0f + erff(v * 0.70710678118654752f));   // exact GELU
          ((unsigned short*)C)[coff + (size_t)(mb + r)*ldc + n] = f2bf(v);
        }
      }
    }
  }
}

// ---------------------------------------------------------------------------
// Row softmax over scores [64][512][512] f32, in-place; writes bf16 probs
// into the first 1024 ushorts of each 2048-byte row (probs lda = 1024).
// One wave per row; scale = 1/sqrt(512).
// ---------------------------------------------------------------------------
template<int CAUSAL>
__global__ __launch_bounds__(256)
void softmax_rows(float* __restrict__ scores)
{
  const int row  = blockIdx.x*4 + (threadIdx.x >> 6);
  const int lane = threadIdx.x & 63;
  const int q = row & 511;
  const float* srow = scores + (size_t)row*512;
  float s[8]; float m = -1e30f;
  #pragma unroll
  for (int i = 0; i < 8; i++){
    const int col = lane*8 + i;
    float v = srow[col] * 0.044194173824159216f;   // 1/sqrt(512)
    if (CAUSAL && col > q) v = -1e30f;
    s[i] = v; m = fmaxf(m, v);
  }
  #pragma unroll
  for (int o = 32; o; o >>= 1) m = fmaxf(m, __shfl_xor(m, o));
  float p[8], sum = 0.f;
  #pragma unroll
  for (int i = 0; i < 8; i++){
    float e = __expf(s[i] - m);
    if (CAUSAL && (lane*8 + i) > q) e = 0.f;
    p[i] = e; sum += e;
  }
  #pragma unroll
  for (int o = 32; o; o >>= 1) sum += __shfl_xor(sum, o);
  const float inv = 1.0f / sum;
  unsigned short* prow = (unsigned short*)scores + (size_t)row*1024;
  #pragma unroll
  for (int i = 0; i < 8; i++) prow[lane*8 + i] = f2bf(p[i] * inv);
}

// ---------------------------------------------------------------------------
// y = LayerNorm(x + sum_{p<ND} partial_p + bias) * g + b.
// BFP=1: partials are bf16 (short8 vector loads); BFP=0: f32.
// ---------------------------------------------------------------------------
template<int WRITE_BF, int ND, int BFP>
__global__ __launch_bounds__(256)
void ln_rows(const float* __restrict__ x, const void* __restrict__ dbase,
             size_t dstride, const float* __restrict__ bias,
             const float* __restrict__ g, const float* __restrict__ bta,
             float* __restrict__ xo, unsigned short* __restrict__ xb)
{
  const int row = blockIdx.x*4 + (threadIdx.x >> 6);
  const int lane = threadIdx.x & 63;
  const float* xr = x + (size_t)row*512;
  float v[8];
  #pragma unroll
  for (int i = 0; i < 8; i++){
    const int c = lane*8 + i;
    v[i] = xr[c] + (bias ? bias[c] : 0.0f);
  }
  #pragma unroll
  for (int p = 0; p < ND; p++){
    if (BFP){
      const unsigned short* db = (const unsigned short*)dbase;
      u16x8 dv = *(const u16x8*)(db + p*dstride + (size_t)row*512 + lane*8);
      #pragma unroll
      for (int i = 0; i < 8; i++) v[i] += bf2f(dv[i]);
    } else {
      const float* db = (const float*)dbase;
      #pragma unroll
      for (int i = 0; i < 8; i++) v[i] += db[p*dstride + (size_t)row*512 + lane*8 + i];
    }
  }
  float sum = 0.f;
  #pragma unroll
  for (int i = 0; i < 8; i++) sum += v[i];
  #pragma unroll
  for (int o = 32; o; o >>= 1) sum += __shfl_xor(sum, o);
  const float mean = sum * (1.0f/512.0f);
  float s2 = 0.f;
  #pragma unroll
  for (int i = 0; i < 8; i++){ const float t = v[i] - mean; s2 += t*t; }
  #pragma unroll
  for (int o = 32; o; o >>= 1) s2 += __shfl_xor(s2, o);
  const float inv = rsqrtf(s2 * (1.0f/512.0f) + 1e-3f);
  #pragma unroll
  for (int i = 0; i < 8; i++){
    const int c = lane*8 + i;
    const float y = (v[i] - mean)*inv*g[c] + bta[c];
    xo[(size_t)row*512 + c] = y;
    if (WRITE_BF) xb[(size_t)row*512 + c] = f2bf(y);
  }
}

__global__ __launch_bounds__(256)
void cast_bf16_k(const float* __restrict__ s, unsigned short* __restrict__ d, int n)
{
  const int i = (blockIdx.x*256 + threadIdx.x)*4;
  if (i < n){
    const float4 v = *(const float4*)(s + i);
    uint2 o;
    o.x = (unsigned)f2bf(v.x) | ((unsigned)f2bf(v.y) << 16);
    o.y = (unsigned)f2bf(v.z) | ((unsigned)f2bf(v.w) << 16);
    *(uint2*)(d + i) = o;
  }
}

// src [R][C] f32 -> dst [C][R] bf16
__global__ __launch_bounds__(256)
void transpose_cast(const float* __restrict__ src, unsigned short* __restrict__ dst, int R, int C)
{
  __shared__ float tile[32][33];
  const int bx = blockIdx.x*32, by = blockIdx.y*32;
  const int tx = threadIdx.x, ty = threadIdx.y;
  #pragma unroll
  for (int i = 0; i < 32; i += 8) tile[ty + i][tx] = src[(size_t)(by + ty + i)*C + bx + tx];
  __syncthreads();
  #pragma unroll
  for (int i = 0; i < 32; i += 8) dst[(size_t)(bx + ty + i)*R + by + tx] = f2bf(tile[tx][ty + i]);
}

// vb [4096 m=(b,s)][4096 n=(h,ko)] bf16  ->  vT [b][h][ko][s] bf16
__global__ __launch_bounds__(256)
void transpose_v(const unsigned short* __restrict__ src, unsigned short* __restrict__ dst)
{
  __shared__ unsigned short t[32][34];
  const int z = blockIdx.z, b = z >> 3, h = z & 7;
  const int s0 = blockIdx.y*32, k0 = blockIdx.x*32;
  const int tx = threadIdx.x & 31, ty4 = (threadIdx.x >> 5) * 4;
  #pragma unroll
  for (int i = 0; i < 4; i++)
    t[ty4 + i][tx] = src[(size_t)(b*512 + s0 + ty4 + i)*4096 + h*512 + k0 + tx];
  __syncthreads();
  unsigned short* d = dst + ((size_t)z*512 + k0)*512 + s0;
  #pragma unroll
  for (int i = 0; i < 4; i++)
    d[(size_t)(ty4 + i)*512 + tx] = t[tx][ty4 + i];
}

// ---------------------------------------------------------------------------
extern "C" void kernel_launch(void* const* d_in, const int* in_sizes, int n_in,
                              void* d_out, int out_size, void* d_ws, size_t ws_size,
                              hipStream_t stream)
{
  (void)in_sizes; (void)n_in; (void)out_size; (void)ws_size;

  const float* in_seq  = (const float*)d_in[0];
  const float* out_seq = (const float*)d_in[1];
  const float* sa_wq = (const float*)d_in[2];  const float* sa_bq = (const float*)d_in[3];
  const float* sa_wk = (const float*)d_in[4];  const float* sa_bk = (const float*)d_in[5];
  const float* sa_wv = (const float*)d_in[6];  const float* sa_bv = (const float*)d_in[7];
  const float* sa_wo = (const float*)d_in[8];  const float* sa_bo = (const float*)d_in[9];
  const float* sa_lng = (const float*)d_in[10]; const float* sa_lnb = (const float*)d_in[11];
  const float* ca_wq = (const float*)d_in[12]; const float* ca_bq = (const float*)d_in[13];
  const float* ca_wk = (const float*)d_in[14]; const float* ca_bk = (const float*)d_in[15];
  const float* ca_wv = (const float*)d_in[16]; const float* ca_bv = (const float*)d_in[17];
  const float* ca_wo = (const float*)d_in[18]; const float* ca_bo = (const float*)d_in[19];
  const float* ca_lng = (const float*)d_in[20]; const float* ca_lnb = (const float*)d_in[21];
  const float* ff_w1 = (const float*)d_in[22]; const float* ff_b1 = (const float*)d_in[23];
  const float* ff_w2 = (const float*)d_in[24]; const float* ff_b2 = (const float*)d_in[25];
  const float* ff_lng = (const float*)d_in[26]; const float* ff_lnb = (const float*)d_in[27];

  char* ws = (char*)d_ws;
  size_t off = 0;
  auto alloc = [&](size_t bytes){ char* p = ws + off; off += (bytes + 255) & ~(size_t)255; return p; };

  unsigned short* wT[8];
  for (int i = 0; i < 8; i++) wT[i] = (unsigned short*)alloc(4096ULL*512*2);
  unsigned short* w1T  = (unsigned short*)alloc(1024ULL*512*2);
  unsigned short* w2T  = (unsigned short*)alloc(512ULL*1024*2);
  unsigned short* xbf  = (unsigned short*)alloc(4096ULL*512*2);
  unsigned short* inbf = (unsigned short*)alloc(4096ULL*512*2);
  unsigned short* qb   = (unsigned short*)alloc(4096ULL*4096*2);   // also FFN hidden
  unsigned short* kb   = (unsigned short*)alloc(4096ULL*4096*2);   // also attn-out
  unsigned short* vT   = (unsigned short*)alloc(64ULL*512*512*2);
  float*          sc   = (float*)alloc(64ULL*512*512*4);           // 64 MB multi-use
  float*          xcur = (float*)alloc(4096ULL*512*4);

  // sc region timeline per stage: vb (V-proj, 33.5 MB) -> consumed by
  // transpose_v -> f32 scores (64 MB, attn GEMM) -> softmax writes bf16
  // probs in-place (row-interleaved, lda 1024 ushorts) -> consumed by PV ->
  // 8 bf16 split-K partial slices (32 MB, out-proj / ff2) -> ln_rows.
  unsigned short* vb   = (unsigned short*)sc;
  unsigned short* part = (unsigned short*)sc;
  const size_t PART_STRIDE = 2097152;   // ushorts per slice (4096*512)

  dim3 tb(32, 8);
  cast_bf16_k<<<2048, 256, 0, stream>>>(out_seq, xbf, 4096*512);
  cast_bf16_k<<<2048, 256, 0, stream>>>(in_seq, inbf, 4096*512);
  // weights -> [N][K] bf16
  transpose_cast<<<dim3(128,16), tb, 0, stream>>>(sa_wq, wT[0], 512, 4096);
  transpose_cast<<<dim3(128,16), tb, 0, stream>>>(sa_wk, wT[1], 512, 4096);
  transpose_cast<<<dim3(128,16), tb, 0, stream>>>(sa_wv, wT[2], 512, 4096);
  transpose_cast<<<dim3(16,128), tb, 0, stream>>>(sa_wo, wT[3], 4096, 512);
  transpose_cast<<<dim3(128,16), tb, 0, stream>>>(ca_wq, wT[4], 512, 4096);
  transpose_cast<<<dim3(128,16), tb, 0, stream>>>(ca_wk, wT[5], 512, 4096);
  transpose_cast<<<dim3(128,16), tb, 0, stream>>>(ca_wv, wT[6], 512, 4096);
  transpose_cast<<<dim3(16,128), tb, 0, stream>>>(ca_wo, wT[7], 4096, 512);
  transpose_cast<<<dim3(32,16),  tb, 0, stream>>>(ff_w1, w1T, 512, 1024);
  transpose_cast<<<dim3(16,32),  tb, 0, stream>>>(ff_w2, w2T, 1024, 512);

  #define G256(MODE, CSK, Apt, Bpt, Cpt, BIAS, M, N, K, LDA, LDB, LDC, Z, aH, aB, bH, bB, cH, cB) \
    gemm256<MODE, CSK><<<dim3((N)/256,(M)/256,(Z)), 512, 0, stream>>>( \
      (const unsigned short*)(Apt), (const unsigned short*)(Bpt), (void*)(Cpt), BIAS, \
      M, N, K, LDA, LDB, LDC, aH, aB, bH, bB, cH, cB)

  // ---- self-attention (causal) ----
  G256(1, 0, xbf, wT[0], qb, sa_bq, 4096, 4096, 512, 512, 512, 4096, 1, 0,0,0,0,0,0);
  G256(1, 0, xbf, wT[1], kb, sa_bk, 4096, 4096, 512, 512, 512, 4096, 1, 0,0,0,0,0,0);
  G256(1, 0, xbf, wT[2], vb, sa_bv, 4096, 4096, 512, 512, 512, 4096, 1, 0,0,0,0,0,0);
  transpose_v<<<dim3(16,16,64), 256, 0, stream>>>(vb, vT);
  G256(0, 1, qb, kb, sc, nullptr, 512, 512, 512, 4096, 4096, 512, 64,
       512, 2097152, 512, 2097152, 262144, 2097152);
  softmax_rows<1><<<8192, 256, 0, stream>>>(sc);
  G256(1, 2, sc, vT, kb, nullptr, 512, 512, 512, 1024, 512, 4096, 64,
       524288, 4194304, 262144, 2097152, 512, 2097152);
  // out-proj: gemm256 split-K=8 (z=head; K=512 each), bf16 partials into `part`
  G256(1, 0, kb, wT[3], part, nullptr, 4096, 512, 512, 4096, 4096, 512, 8,
       512, 0, 512, 0, PART_STRIDE, 0);
  ln_rows<1, 8, 1><<<1024, 256, 0, stream>>>(out_seq, part, PART_STRIDE,
                                             sa_bo, sa_lng, sa_lnb, xcur, xbf);

  // ---- cross-attention ----
  G256(1, 0, xbf,  wT[4], qb, ca_bq, 4096, 4096, 512, 512, 512, 4096, 1, 0,0,0,0,0,0);
  G256(1, 0, inbf, wT[5], kb, ca_bk, 4096, 4096, 512, 512, 512, 4096, 1, 0,0,0,0,0,0);
  G256(1, 0, inbf, wT[6], vb, ca_bv, 4096, 4096, 512, 512, 512, 4096, 1, 0,0,0,0,0,0);
  transpose_v<<<dim3(16,16,64), 256, 0, stream>>>(vb, vT);
  G256(0, 0, qb, kb, sc, nullptr, 512, 512, 512, 4096, 4096, 512, 64,
       512, 2097152, 512, 2097152, 262144, 2097152);
  softmax_rows<0><<<8192, 256, 0, stream>>>(sc);
  G256(1, 0, sc, vT, kb, nullptr, 512, 512, 512, 1024, 512, 4096, 64,
       524288, 4194304, 262144, 2097152, 512, 2097152);
  G256(1, 0, kb, wT[7], part, nullptr, 4096, 512, 512, 4096, 4096, 512, 8,
       512, 0, 512, 0, PART_STRIDE, 0);
  ln_rows<1, 8, 1><<<1024, 256, 0, stream>>>(xcur, part, PART_STRIDE,
                                             ca_bo, ca_lng, ca_lnb, xcur, xbf);

  // ---- FFN ----
  // ff1: gemm256 GELU, grid (4,16) = 64 blocks (all co-resident, 1/CU)
  G256(2, 0, xbf, w1T, qb, ff_b1, 4096, 1024, 512, 512, 512, 1024, 1, 0,0,0,0,0,0);
  // ff2: gemm256 split-K=8 (K=128 each), bf16 partials
  G256(1, 0, qb, w2T, part, nullptr, 4096, 512, 128, 1024, 1024, 512, 8,
       128, 0, 128, 0, PART_STRIDE, 0);
  ln_rows<0, 8, 1><<<1024, 256, 0, stream>>>(xcur, part, PART_STRIDE,
                                             ff_b2, ff_lng, ff_lnb, (float*)d_out, nullptr);

  #undef G256
}

// Round 14
// 506.684 us; speedup vs baseline: 1.1404x; 1.1404x over previous
//
#include <hip/hip_runtime.h>
#include <math.h>

#define DEV __device__ __forceinline__

typedef __bf16 bf16x8 __attribute__((ext_vector_type(8)));
typedef float f32x4 __attribute__((ext_vector_type(4)));
typedef unsigned short u16x8 __attribute__((ext_vector_type(8)));

typedef const __attribute__((address_space(1))) void gv_t;
typedef __attribute__((address_space(3))) void lv_t;

DEV unsigned short f2bf(float f){
  unsigned int u = __float_as_uint(f);
  u += 0x7fffu + ((u >> 16) & 1u);     // round-to-nearest-even
  return (unsigned short)(u >> 16);
}
DEV float bf2f(unsigned short u){ return __uint_as_float((unsigned)u << 16); }

DEV void gload16(const void* g, void* l){
  __builtin_amdgcn_global_load_lds((gv_t*)g, (lv_t*)l, 16, 0, 0);
}

// T1 chunked XCD swizzle (bijective when nwg%8==0, identity otherwise).
DEV void xcd_decode(int& bx, int& by, int& bz){
  const int gx = gridDim.x, gy = gridDim.y;
  const int nwg = gx * gy * gridDim.z;
  int lin = blockIdx.x + gx*(blockIdx.y + gy*blockIdx.z);
  if ((nwg & 7) == 0) lin = (lin & 7)*(nwg >> 3) + (lin >> 3);
  bx = lin % gx; const int t = lin / gx;
  by = t % gy;  bz = t / gy;
}

struct Proj3 {
  const unsigned short* A[3];
  const unsigned short* B[3];
  unsigned short*       C[3];
  const float*          bias[3];
};

// ---------------------------------------------------------------------------
// qkv256: three independent 4096x4096x512 projections in ONE dispatch
// (bz = projection id; 768 blocks fill all 256 CUs at 2/CU).  Same verified
// gemm256 body: 256x256 tile, BK=64, 8 waves, 2-phase dbuf, XOR swizzle.
// Fixed: lda=ldb=512, ldc=4096, bf16 store (+bias).
// ---------------------------------------------------------------------------
__global__ __launch_bounds__(512, 2)
void qkv256(Proj3 pr)
{
  __shared__ unsigned short Ab[2][16384];
  __shared__ unsigned short Bb[2][16384];

  int bxi, byi, bzi; xcd_decode(bxi, byi, bzi);
  const int m0 = byi*256, n0 = bxi*256;
  const unsigned short* A = pr.A[bzi];
  const unsigned short* B = pr.B[bzi];
  unsigned short*       C = pr.C[bzi];
  const float*       bias = pr.bias[bzi];

  const int tid = threadIdx.x, lane = tid & 63, w = tid >> 6;
  const int wr = w >> 2, wc = w & 3;
  const int l15 = lane & 15, l4 = lane >> 4;

  const int r8  = tid >> 3;
  const int sc8 = ((tid & 7) ^ (r8 & 7)) * 8;

  auto stage = [&](int buf, int kt){
    #pragma unroll
    for (int j = 0; j < 4; j++){
      gload16(A + (size_t)(m0 + j*64 + r8)*512 + kt + sc8, &Ab[buf][j*4096 + tid*8]);
      gload16(B + (size_t)(n0 + j*64 + r8)*512 + kt + sc8, &Bb[buf][j*4096 + tid*8]);
    }
  };

  f32x4 acc[8][4] = {};

  stage(0, 0);
  __syncthreads();
  for (int t = 0; t < 8; t++){
    const int cur = t & 1;
    if (t + 1 < 8) stage(cur ^ 1, (t+1)*64);

    bf16x8 bfr[4][2];
    #pragma unroll
    for (int fc = 0; fc < 4; fc++){
      const int R = wc*64 + fc*16 + l15;
      #pragma unroll
      for (int kc = 0; kc < 2; kc++){
        const int cc = (kc*32 + l4*8) ^ ((R & 7) * 8);
        bfr[fc][kc] = *(const bf16x8*)&Bb[cur][R*64 + cc];
      }
    }
    #pragma unroll
    for (int fr = 0; fr < 8; fr++){
      bf16x8 ar[2];
      const int R = wr*128 + fr*16 + l15;
      #pragma unroll
      for (int kc = 0; kc < 2; kc++){
        const int cc = (kc*32 + l4*8) ^ ((R & 7) * 8);
        ar[kc] = *(const bf16x8*)&Ab[cur][R*64 + cc];
      }
      #pragma unroll
      for (int fc = 0; fc < 4; fc++)
        #pragma unroll
        for (int kc = 0; kc < 2; kc++)
          acc[fr][fc] = __builtin_amdgcn_mfma_f32_16x16x32_bf16(
              ar[kc], bfr[fc][kc], acc[fr][fc], 0, 0, 0);
    }
    __syncthreads();
  }

  #pragma unroll
  for (int fr = 0; fr < 8; fr++){
    const int mb = m0 + wr*128 + fr*16 + l4*4;
    #pragma unroll
    for (int fc = 0; fc < 4; fc++){
      const int n = n0 + wc*64 + fc*16 + l15;
      const float bv = bias[n];
      #pragma unroll
      for (int r = 0; r < 4; r++)
        C[(size_t)(mb + r)*4096 + n] = f2bf(acc[fr][fc][r] + bv);
    }
  }
}

// ---------------------------------------------------------------------------
// gemm256: 256x256 tile, BK=64, 8 waves, 2-phase dbuf, XOR swizzle.
// CMODE: 0=f32 store, 1=bf16 store. CSK: 0 none, 1 causal block-skip,
// 2 causal K-clamp.  Batched over bz (z = b*8+h or k-slice).
// ---------------------------------------------------------------------------
template<int CMODE, int CSK>
__global__ __launch_bounds__(512, 2)
void gemm256(const unsigned short* __restrict__ A, const unsigned short* __restrict__ B,
             void* __restrict__ C, const float* __restrict__ bias,
             int M, int N, int K, int lda, int ldb, int ldc,
             size_t aOffH, size_t aOffB, size_t bOffH, size_t bOffB,
             size_t cOffH, size_t cOffB)
{
  __shared__ unsigned short Ab[2][16384];
  __shared__ unsigned short Bb[2][16384];

  int bxi, byi, bzi; xcd_decode(bxi, byi, bzi);
  const int m0 = byi*256, n0 = bxi*256;
  if (CSK == 1 && n0 > m0 + 255) return;     // fully-masked causal block

  const int z = bzi, bb = z >> 3, hh = z & 7;
  A += (size_t)bb*aOffB + (size_t)hh*aOffH;
  B += (size_t)bb*bOffB + (size_t)hh*bOffH;
  const size_t coff = (size_t)bb*cOffB + (size_t)hh*cOffH;

  const int tid = threadIdx.x, lane = tid & 63, w = tid >> 6;
  const int wr = w >> 2, wc = w & 3;
  const int l15 = lane & 15, l4 = lane >> 4;

  int Keff = K;
  if (CSK == 2) Keff = (m0 + 256 < K) ? (m0 + 256) : K;
  const int nt = Keff >> 6;

  const int r8  = tid >> 3;
  const int sc8 = ((tid & 7) ^ (r8 & 7)) * 8;

  auto stage = [&](int buf, int kt){
    #pragma unroll
    for (int j = 0; j < 4; j++){
      gload16(A + (size_t)(m0 + j*64 + r8)*lda + kt + sc8, &Ab[buf][j*4096 + tid*8]);
      gload16(B + (size_t)(n0 + j*64 + r8)*ldb + kt + sc8, &Bb[buf][j*4096 + tid*8]);
    }
  };

  f32x4 acc[8][4] = {};

  stage(0, 0);
  __syncthreads();
  for (int t = 0; t < nt; t++){
    const int cur = t & 1;
    if (t + 1 < nt) stage(cur ^ 1, (t+1)*64);

    bf16x8 bfr[4][2];
    #pragma unroll
    for (int fc = 0; fc < 4; fc++){
      const int R = wc*64 + fc*16 + l15;
      #pragma unroll
      for (int kc = 0; kc < 2; kc++){
        const int cc = (kc*32 + l4*8) ^ ((R & 7) * 8);
        bfr[fc][kc] = *(const bf16x8*)&Bb[cur][R*64 + cc];
      }
    }
    #pragma unroll
    for (int fr = 0; fr < 8; fr++){
      bf16x8 ar[2];
      const int R = wr*128 + fr*16 + l15;
      #pragma unroll
      for (int kc = 0; kc < 2; kc++){
        const int cc = (kc*32 + l4*8) ^ ((R & 7) * 8);
        ar[kc] = *(const bf16x8*)&Ab[cur][R*64 + cc];
      }
      #pragma unroll
      for (int fc = 0; fc < 4; fc++)
        #pragma unroll
        for (int kc = 0; kc < 2; kc++)
          acc[fr][fc] = __builtin_amdgcn_mfma_f32_16x16x32_bf16(
              ar[kc], bfr[fc][kc], acc[fr][fc], 0, 0, 0);
    }
    __syncthreads();
  }

  #pragma unroll
  for (int fr = 0; fr < 8; fr++){
    const int mb = m0 + wr*128 + fr*16 + l4*4;
    #pragma unroll
    for (int fc = 0; fc < 4; fc++){
      const int n = n0 + wc*64 + fc*16 + l15;
      const float bv = bias ? bias[n] : 0.0f;
      #pragma unroll
      for (int r = 0; r < 4; r++){
        const float v = acc[fr][fc][r] + bv;
        if (CMODE == 0) ((float*)C)[coff + (size_t)(mb + r)*ldc + n] = v;
        else            ((unsigned short*)C)[coff + (size_t)(mb + r)*ldc + n] = f2bf(v);
      }
    }
  }
}

// ---------------------------------------------------------------------------
// gemm_bt: 128x128 tile, BK=64, 4 waves, 2-phase dbuf (ff1 only).
// CMODE: 0=f32, 1=bf16, 2=bf16 gelu.
// ---------------------------------------------------------------------------
template<int CMODE>
__global__ __launch_bounds__(256, 2)
void gemm_bt(const unsigned short* __restrict__ A, const unsigned short* __restrict__ B,
             void* __restrict__ C, const float* __restrict__ bias,
             int M, int N, int K, int lda, int ldb, int ldc)
{
  __shared__ unsigned short Ab[2][8192];
  __shared__ unsigned short Bb[2][8192];

  int bxi, byi, bzi; xcd_decode(bxi, byi, bzi);
  (void)bzi;
  const int m0 = byi*128, n0 = bxi*128;

  const int tid = threadIdx.x, lane = tid & 63, w = tid >> 6;
  const int wr = w >> 1, wc = w & 1;
  const int l15 = lane & 15, l4 = lane >> 4;
  const int nt = K >> 6;

  const int r8  = tid >> 3;
  const int sc8 = ((tid & 7) ^ (r8 & 7)) * 8;

  auto stage = [&](int buf, int kt){
    #pragma unroll
    for (int j = 0; j < 4; j++){
      gload16(A + (size_t)(m0 + j*32 + r8)*lda + kt + sc8, &Ab[buf][j*2048 + tid*8]);
      gload16(B + (size_t)(n0 + j*32 + r8)*ldb + kt + sc8, &Bb[buf][j*2048 + tid*8]);
    }
  };

  f32x4 acc[4][4] = {};

  stage(0, 0);
  __syncthreads();
  for (int t = 0; t < nt; t++){
    const int cur = t & 1;
    if (t + 1 < nt) stage(cur ^ 1, (t+1)*64);

    bf16x8 af[4][2], bfr[4][2];
    #pragma unroll
    for (int i = 0; i < 4; i++){
      const int Ra = wr*64 + i*16 + l15;
      const int Rb = wc*64 + i*16 + l15;
      #pragma unroll
      for (int kc = 0; kc < 2; kc++){
        const int ca = (kc*32 + l4*8) ^ ((Ra & 7) * 8);
        const int cb = (kc*32 + l4*8) ^ ((Rb & 7) * 8);
        af[i][kc]  = *(const bf16x8*)&Ab[cur][Ra*64 + ca];
        bfr[i][kc] = *(const bf16x8*)&Bb[cur][Rb*64 + cb];
      }
    }
    #pragma unroll
    for (int i = 0; i < 4; i++)
      #pragma unroll
      for (int jj = 0; jj < 4; jj++)
        #pragma unroll
        for (int kc = 0; kc < 2; kc++)
          acc[i][jj] = __builtin_amdgcn_mfma_f32_16x16x32_bf16(
              af[i][kc], bfr[jj][kc], acc[i][jj], 0, 0, 0);
    __syncthreads();
  }

  #pragma unroll
  for (int i = 0; i < 4; i++){
    const int mbase = m0 + wr*64 + i*16 + l4*4;
    #pragma unroll
    for (int jj = 0; jj < 4; jj++){
      const int n = n0 + wc*64 + jj*16 + l15;
      const float bv = bias ? bias[n] : 0.0f;
      #pragma unroll
      for (int r = 0; r < 4; r++){
        const int m = mbase + r;
        float v = acc[i][jj][r] + bv;
        if (CMODE == 0){
          ((float*)C)[(size_t)m*ldc + n] = v;
        } else if (CMODE == 1){
          ((unsigned short*)C)[(size_t)m*ldc + n] = f2bf(v);
        } else {
          v = 0.5f * v * (1.0f + erff(v * 0.70710678118654752f));   // exact GELU
          ((unsigned short*)C)[(size_t)m*ldc + n] = f2bf(v);
        }
      }
    }
  }
}

// ---------------------------------------------------------------------------
template<int CAUSAL>
__global__ __launch_bounds__(256)
void softmax_rows(float* __restrict__ scores)
{
  const int row  = blockIdx.x*4 + (threadIdx.x >> 6);
  const int lane = threadIdx.x & 63;
  const int q = row & 511;
  const float* srow = scores + (size_t)row*512;
  float s[8]; float m = -1e30f;
  #pragma unroll
  for (int i = 0; i < 8; i++){
    const int col = lane*8 + i;
    float v = srow[col] * 0.044194173824159216f;   // 1/sqrt(512)
    if (CAUSAL && col > q) v = -1e30f;
    s[i] = v; m = fmaxf(m, v);
  }
  #pragma unroll
  for (int o = 32; o; o >>= 1) m = fmaxf(m, __shfl_xor(m, o));
  float p[8], sum = 0.f;
  #pragma unroll
  for (int i = 0; i < 8; i++){
    float e = __expf(s[i] - m);
    if (CAUSAL && (lane*8 + i) > q) e = 0.f;
    p[i] = e; sum += e;
  }
  #pragma unroll
  for (int o = 32; o; o >>= 1) sum += __shfl_xor(sum, o);
  const float inv = 1.0f / sum;
  unsigned short* prow = (unsigned short*)scores + (size_t)row*1024;
  #pragma unroll
  for (int i = 0; i < 8; i++) prow[lane*8 + i] = f2bf(p[i] * inv);
}

// ---------------------------------------------------------------------------
// y = LayerNorm(x + sum_{p<ND} partial_p + bias) * g + b.
// BFP=1: partials are bf16 (short8 vector loads); BFP=0: f32.
// ---------------------------------------------------------------------------
template<int WRITE_BF, int ND, int BFP>
__global__ __launch_bounds__(256)
void ln_rows(const float* __restrict__ x, const void* __restrict__ dbase,
             size_t dstride, const float* __restrict__ bias,
             const float* __restrict__ g, const float* __restrict__ bta,
             float* __restrict__ xo, unsigned short* __restrict__ xb)
{
  const int row = blockIdx.x*4 + (threadIdx.x >> 6);
  const int lane = threadIdx.x & 63;
  const float* xr = x + (size_t)row*512;
  float v[8];
  #pragma unroll
  for (int i = 0; i < 8; i++){
    const int c = lane*8 + i;
    v[i] = xr[c] + (bias ? bias[c] : 0.0f);
  }
  #pragma unroll
  for (int p = 0; p < ND; p++){
    if (BFP){
      const unsigned short* db = (const unsigned short*)dbase;
      u16x8 dv = *(const u16x8*)(db + p*dstride + (size_t)row*512 + lane*8);
      #pragma unroll
      for (int i = 0; i < 8; i++) v[i] += bf2f(dv[i]);
    } else {
      const float* db = (const float*)dbase;
      #pragma unroll
      for (int i = 0; i < 8; i++) v[i] += db[p*dstride + (size_t)row*512 + lane*8 + i];
    }
  }
  float sum = 0.f;
  #pragma unroll
  for (int i = 0; i < 8; i++) sum += v[i];
  #pragma unroll
  for (int o = 32; o; o >>= 1) sum += __shfl_xor(sum, o);
  const float mean = sum * (1.0f/512.0f);
  float s2 = 0.f;
  #pragma unroll
  for (int i = 0; i < 8; i++){ const float t = v[i] - mean; s2 += t*t; }
  #pragma unroll
  for (int o = 32; o; o >>= 1) s2 += __shfl_xor(s2, o);
  const float inv = rsqrtf(s2 * (1.0f/512.0f) + 1e-3f);
  #pragma unroll
  for (int i = 0; i < 8; i++){
    const int c = lane*8 + i;
    const float y = (v[i] - mean)*inv*g[c] + bta[c];
    xo[(size_t)row*512 + c] = y;
    if (WRITE_BF) xb[(size_t)row*512 + c] = f2bf(y);
  }
}

struct Cast2 { const float* s[2]; unsigned short* d[2]; };

__global__ __launch_bounds__(256)
void cast_bf16_k2(Cast2 a, int n)
{
  const int z = blockIdx.y;
  const int i = (blockIdx.x*256 + threadIdx.x)*4;
  if (i < n){
    const float4 v = *(const float4*)(a.s[z] + i);
    uint2 o;
    o.x = (unsigned)f2bf(v.x) | ((unsigned)f2bf(v.y) << 16);
    o.y = (unsigned)f2bf(v.z) | ((unsigned)f2bf(v.w) << 16);
    *(uint2*)(a.d[z] + i) = o;
  }
}

struct TC8 { const float* s[8]; unsigned short* d[8]; };

// src [R][C] f32 -> dst [C][R] bf16 ; z = blockIdx.z selects tensor
__global__ __launch_bounds__(256)
void transpose_cast8(TC8 a, int R, int C)
{
  __shared__ float tile[32][33];
  const int z = blockIdx.z;
  const float* src = a.s[z];
  unsigned short* dst = a.d[z];
  const int bx = blockIdx.x*32, by = blockIdx.y*32;
  const int tx = threadIdx.x & 31, ty = threadIdx.x >> 5;   // 256 thr = 32x8
  #pragma unroll
  for (int i = 0; i < 32; i += 8) tile[ty + i][tx] = src[(size_t)(by + ty + i)*C + bx + tx];
  __syncthreads();
  #pragma unroll
  for (int i = 0; i < 32; i += 8) dst[(size_t)(bx + ty + i)*R + by + tx] = f2bf(tile[tx][ty + i]);
}

// vb [4096 m=(b,s)][4096 n=(h,ko)] bf16  ->  vT [b][h][ko][s] bf16
__global__ __launch_bounds__(256)
void transpose_v(const unsigned short* __restrict__ src, unsigned short* __restrict__ dst)
{
  __shared__ unsigned short t[32][34];
  const int z = blockIdx.z, b = z >> 3, h = z & 7;
  const int s0 = blockIdx.y*32, k0 = blockIdx.x*32;
  const int tx = threadIdx.x & 31, ty4 = (threadIdx.x >> 5) * 4;
  #pragma unroll
  for (int i = 0; i < 4; i++)
    t[ty4 + i][tx] = src[(size_t)(b*512 + s0 + ty4 + i)*4096 + h*512 + k0 + tx];
  __syncthreads();
  unsigned short* d = dst + ((size_t)z*512 + k0)*512 + s0;
  #pragma unroll
  for (int i = 0; i < 4; i++)
    d[(size_t)(ty4 + i)*512 + tx] = t[tx][ty4 + i];
}

// ---------------------------------------------------------------------------
extern "C" void kernel_launch(void* const* d_in, const int* in_sizes, int n_in,
                              void* d_out, int out_size, void* d_ws, size_t ws_size,
                              hipStream_t stream)
{
  (void)in_sizes; (void)n_in; (void)out_size; (void)ws_size;

  const float* in_seq  = (const float*)d_in[0];
  const float* out_seq = (const float*)d_in[1];
  const float* sa_wq = (const float*)d_in[2];  const float* sa_bq = (const float*)d_in[3];
  const float* sa_wk = (const float*)d_in[4];  const float* sa_bk = (const float*)d_in[5];
  const float* sa_wv = (const float*)d_in[6];  const float* sa_bv = (const float*)d_in[7];
  const float* sa_wo = (const float*)d_in[8];  const float* sa_bo = (const float*)d_in[9];
  const float* sa_lng = (const float*)d_in[10]; const float* sa_lnb = (const float*)d_in[11];
  const float* ca_wq = (const float*)d_in[12]; const float* ca_bq = (const float*)d_in[13];
  const float* ca_wk = (const float*)d_in[14]; const float* ca_bk = (const float*)d_in[15];
  const float* ca_wv = (const float*)d_in[16]; const float* ca_bv = (const float*)d_in[17];
  const float* ca_wo = (const float*)d_in[18]; const float* ca_bo = (const float*)d_in[19];
  const float* ca_lng = (const float*)d_in[20]; const float* ca_lnb = (const float*)d_in[21];
  const float* ff_w1 = (const float*)d_in[22]; const float* ff_b1 = (const float*)d_in[23];
  const float* ff_w2 = (const float*)d_in[24]; const float* ff_b2 = (const float*)d_in[25];
  const float* ff_lng = (const float*)d_in[26]; const float* ff_lnb = (const float*)d_in[27];

  char* ws = (char*)d_ws;
  size_t off = 0;
  auto alloc = [&](size_t bytes){ char* p = ws + off; off += (bytes + 255) & ~(size_t)255; return p; };

  unsigned short* wT[8];
  for (int i = 0; i < 8; i++) wT[i] = (unsigned short*)alloc(4096ULL*512*2);
  unsigned short* w1T  = (unsigned short*)alloc(1024ULL*512*2);
  unsigned short* w2T  = (unsigned short*)alloc(512ULL*1024*2);
  unsigned short* xbf  = (unsigned short*)alloc(4096ULL*512*2);
  unsigned short* inbf = (unsigned short*)alloc(4096ULL*512*2);
  unsigned short* qb   = (unsigned short*)alloc(4096ULL*4096*2);   // also FFN hidden
  unsigned short* kb   = (unsigned short*)alloc(4096ULL*4096*2);   // also attn-out
  unsigned short* vT   = (unsigned short*)alloc(64ULL*512*512*2);
  float*          sc   = (float*)alloc(64ULL*512*512*4);           // 64 MB multi-use
  float*          xcur = (float*)alloc(4096ULL*512*4);

  // sc region timeline: vb (V-proj) -> transpose_v -> f32 scores -> bf16
  // probs in-place -> PV -> 8 bf16 split-K partial slices -> ln_rows.
  unsigned short* vb   = (unsigned short*)sc;
  unsigned short* part = (unsigned short*)sc;
  const size_t PART_STRIDE = 2097152;   // ushorts per slice (4096*512)

  // ---- prologue (merged) ----
  Cast2 c2{{out_seq, in_seq}, {xbf, inbf}};
  cast_bf16_k2<<<dim3(2048,2), 256, 0, stream>>>(c2, 4096*512);

  TC8 tqkv{{sa_wq, sa_wk, sa_wv, ca_wq, ca_wk, ca_wv, nullptr, nullptr},
           {wT[0], wT[1], wT[2], wT[4], wT[5], wT[6], nullptr, nullptr}};
  transpose_cast8<<<dim3(128,16,6), 256, 0, stream>>>(tqkv, 512, 4096);
  TC8 two{{sa_wo, ca_wo, nullptr,nullptr,nullptr,nullptr,nullptr,nullptr},
          {wT[3], wT[7], nullptr,nullptr,nullptr,nullptr,nullptr,nullptr}};
  transpose_cast8<<<dim3(16,128,2), 256, 0, stream>>>(two, 4096, 512);
  TC8 tw1{{ff_w1, nullptr,nullptr,nullptr,nullptr,nullptr,nullptr,nullptr},
          {w1T, nullptr,nullptr,nullptr,nullptr,nullptr,nullptr,nullptr}};
  transpose_cast8<<<dim3(32,16,1), 256, 0, stream>>>(tw1, 512, 1024);
  TC8 tw2{{ff_w2, nullptr,nullptr,nullptr,nullptr,nullptr,nullptr,nullptr},
          {w2T, nullptr,nullptr,nullptr,nullptr,nullptr,nullptr,nullptr}};
  transpose_cast8<<<dim3(16,32,1), 256, 0, stream>>>(tw2, 1024, 512);

  #define G256(MODE, CSK, Apt, Bpt, Cpt, BIAS, M, N, K, LDA, LDB, LDC, Z, aH, aB, bH, bB, cH, cB) \
    gemm256<MODE, CSK><<<dim3((N)/256,(M)/256,(Z)), 512, 0, stream>>>( \
      (const unsigned short*)(Apt), (const unsigned short*)(Bpt), (void*)(Cpt), BIAS, \
      M, N, K, LDA, LDB, LDC, aH, aB, bH, bB, cH, cB)

  // ---- self-attention (causal) ----
  Proj3 saP{{xbf, xbf, xbf}, {wT[0], wT[1], wT[2]}, {qb, kb, vb}, {sa_bq, sa_bk, sa_bv}};
  qkv256<<<dim3(16,16,3), 512, 0, stream>>>(saP);
  transpose_v<<<dim3(16,16,64), 256, 0, stream>>>(vb, vT);
  G256(0, 1, qb, kb, sc, nullptr, 512, 512, 512, 4096, 4096, 512, 64,
       512, 2097152, 512, 2097152, 262144, 2097152);
  softmax_rows<1><<<8192, 256, 0, stream>>>(sc);
  G256(1, 2, sc, vT, kb, nullptr, 512, 512, 512, 1024, 512, 4096, 64,
       524288, 4194304, 262144, 2097152, 512, 2097152);
  G256(1, 0, kb, wT[3], part, nullptr, 4096, 512, 512, 4096, 4096, 512, 8,
       512, 0, 512, 0, PART_STRIDE, 0);
  ln_rows<1, 8, 1><<<1024, 256, 0, stream>>>(out_seq, part, PART_STRIDE,
                                             sa_bo, sa_lng, sa_lnb, xcur, xbf);

  // ---- cross-attention ----
  Proj3 caP{{xbf, inbf, inbf}, {wT[4], wT[5], wT[6]}, {qb, kb, vb}, {ca_bq, ca_bk, ca_bv}};
  qkv256<<<dim3(16,16,3), 512, 0, stream>>>(caP);
  transpose_v<<<dim3(16,16,64), 256, 0, stream>>>(vb, vT);
  G256(0, 0, qb, kb, sc, nullptr, 512, 512, 512, 4096, 4096, 512, 64,
       512, 2097152, 512, 2097152, 262144, 2097152);
  softmax_rows<0><<<8192, 256, 0, stream>>>(sc);
  G256(1, 0, sc, vT, kb, nullptr, 512, 512, 512, 1024, 512, 4096, 64,
       524288, 4194304, 262144, 2097152, 512, 2097152);
  G256(1, 0, kb, wT[7], part, nullptr, 4096, 512, 512, 4096, 4096, 512, 8,
       512, 0, 512, 0, PART_STRIDE, 0);
  ln_rows<1, 8, 1><<<1024, 256, 0, stream>>>(xcur, part, PART_STRIDE,
                                             ca_bo, ca_lng, ca_lnb, xcur, xbf);

  // ---- FFN ----
  // ff1: gemm_bt GELU (256 blocks; R12 proven config)
  gemm_bt<2><<<dim3(8,32,1), 256, 0, stream>>>(
      xbf, w1T, (void*)qb, ff_b1, 4096, 1024, 512, 512, 512, 1024);
  // ff2: gemm256 split-K=8 (K=128 each), bf16 partials
  G256(1, 0, qb, w2T, part, nullptr, 4096, 512, 128, 1024, 1024, 512, 8,
       128, 0, 128, 0, PART_STRIDE, 0);
  ln_rows<0, 8, 1><<<1024, 256, 0, stream>>>(xcur, part, PART_STRIDE,
                                             ff_b2, ff_lng, ff_lnb, (float*)d_out, nullptr);

  #undef G256
}

// Round 15
// 498.759 us; speedup vs baseline: 1.1586x; 1.0159x over previous
//
#include <hip/hip_runtime.h>
#include <math.h>

#define DEV __device__ __forceinline__

typedef __bf16 bf16x8 __attribute__((ext_vector_type(8)));
typedef float f32x4 __attribute__((ext_vector_type(4)));
typedef unsigned short u16x8 __attribute__((ext_vector_type(8)));

typedef const __attribute__((address_space(1))) void gv_t;
typedef __attribute__((address_space(3))) void lv_t;

DEV unsigned short f2bf(float f){
  unsigned int u = __float_as_uint(f);
  u += 0x7fffu + ((u >> 16) & 1u);     // round-to-nearest-even
  return (unsigned short)(u >> 16);
}
DEV float bf2f(unsigned short u){ return __uint_as_float((unsigned)u << 16); }

DEV void gload16(const void* g, void* l){
  __builtin_amdgcn_global_load_lds((gv_t*)g, (lv_t*)l, 16, 0, 0);
}

// T1 chunked XCD swizzle (bijective when nwg%8==0, identity otherwise).
DEV void xcd_decode(int& bx, int& by, int& bz){
  const int gx = gridDim.x, gy = gridDim.y;
  const int nwg = gx * gy * gridDim.z;
  int lin = blockIdx.x + gx*(blockIdx.y + gy*blockIdx.z);
  if ((nwg & 7) == 0) lin = (lin & 7)*(nwg >> 3) + (lin >> 3);
  bx = lin % gx; const int t = lin / gx;
  by = t % gy;  bz = t / gy;
}

struct Proj3 {
  const unsigned short* A[3];
  const unsigned short* B[3];
  unsigned short*       C[3];
  const float*          bias[3];
};

// ---------------------------------------------------------------------------
// qkv256: three 4096x4096x512 projections in one dispatch (R14 body, 2-phase;
// serves as the in-bench CONTROL for the new gemm256 schedule this round).
// ---------------------------------------------------------------------------
__global__ __launch_bounds__(512, 2)
void qkv256(Proj3 pr)
{
  __shared__ unsigned short Ab[2][16384];
  __shared__ unsigned short Bb[2][16384];

  int bxi, byi, bzi; xcd_decode(bxi, byi, bzi);
  const int m0 = byi*256, n0 = bxi*256;
  const unsigned short* A = pr.A[bzi];
  const unsigned short* B = pr.B[bzi];
  unsigned short*       C = pr.C[bzi];
  const float*       bias = pr.bias[bzi];

  const int tid = threadIdx.x, lane = tid & 63, w = tid >> 6;
  const int wr = w >> 2, wc = w & 3;
  const int l15 = lane & 15, l4 = lane >> 4;

  const int r8  = tid >> 3;
  const int sc8 = ((tid & 7) ^ (r8 & 7)) * 8;

  auto stage = [&](int buf, int kt){
    #pragma unroll
    for (int j = 0; j < 4; j++){
      gload16(A + (size_t)(m0 + j*64 + r8)*512 + kt + sc8, &Ab[buf][j*4096 + tid*8]);
      gload16(B + (size_t)(n0 + j*64 + r8)*512 + kt + sc8, &Bb[buf][j*4096 + tid*8]);
    }
  };

  f32x4 acc[8][4] = {};

  stage(0, 0);
  __syncthreads();
  for (int t = 0; t < 8; t++){
    const int cur = t & 1;
    if (t + 1 < 8) stage(cur ^ 1, (t+1)*64);

    bf16x8 bfr[4][2];
    #pragma unroll
    for (int fc = 0; fc < 4; fc++){
      const int R = wc*64 + fc*16 + l15;
      #pragma unroll
      for (int kc = 0; kc < 2; kc++){
        const int cc = (kc*32 + l4*8) ^ ((R & 7) * 8);
        bfr[fc][kc] = *(const bf16x8*)&Bb[cur][R*64 + cc];
      }
    }
    #pragma unroll
    for (int fr = 0; fr < 8; fr++){
      bf16x8 ar[2];
      const int R = wr*128 + fr*16 + l15;
      #pragma unroll
      for (int kc = 0; kc < 2; kc++){
        const int cc = (kc*32 + l4*8) ^ ((R & 7) * 8);
        ar[kc] = *(const bf16x8*)&Ab[cur][R*64 + cc];
      }
      #pragma unroll
      for (int fc = 0; fc < 4; fc++)
        #pragma unroll
        for (int kc = 0; kc < 2; kc++)
          acc[fr][fc] = __builtin_amdgcn_mfma_f32_16x16x32_bf16(
              ar[kc], bfr[fc][kc], acc[fr][fc], 0, 0, 0);
    }
    __syncthreads();
  }

  #pragma unroll
  for (int fr = 0; fr < 8; fr++){
    const int mb = m0 + wr*128 + fr*16 + l4*4;
    #pragma unroll
    for (int fc = 0; fc < 4; fc++){
      const int n = n0 + wc*64 + fc*16 + l15;
      const float bv = bias[n];
      #pragma unroll
      for (int r = 0; r < 4; r++)
        C[(size_t)(mb + r)*4096 + n] = f2bf(acc[fr][fc][r] + bv);
    }
  }
}

// ---------------------------------------------------------------------------
// gemm256 (NEW): 256x256 tile, BK=64, 8 waves, half-tile staging with COUNTED
// vmcnt (T3+T4) + setprio (T5) + XOR swizzle (T2).
// LDS: A,B each [2 buf][2 half(128 rows)][64 k].  Per K-tile quad = 4 subs:
//   sub s: ds_read frags (B all at s=0; A fr={2s,2s+1}), issue ONE half stage,
//          lgkmcnt(0)+sched_barrier, setprio(1), 16 MFMA, setprio(0), s_barrier.
// Stage map (race-free): s0/1 -> A-halves(Q+1) into buf cur^1 (held tile Q-1,
// done); s2/3 -> B-halves(Q+2) into buf cur (B(Q) reads certified sub0).
// Quad fence: vmcnt(4) mid-loop (2 halves in flight), vmcnt(0) final quad.
// CMODE: 0=f32, 1=bf16. CSK: 0 none, 1 causal block-skip, 2 causal K-clamp.
// ---------------------------------------------------------------------------
template<int CMODE, int CSK>
__global__ __launch_bounds__(512, 2)
void gemm256(const unsigned short* __restrict__ A, const unsigned short* __restrict__ B,
             void* __restrict__ C, const float* __restrict__ bias,
             int M, int N, int K, int lda, int ldb, int ldc,
             size_t aOffH, size_t aOffB, size_t bOffH, size_t bOffB,
             size_t cOffH, size_t cOffB)
{
  __shared__ unsigned short Ab[2][2][8192];   // [buf][half][128*64]
  __shared__ unsigned short Bb[2][2][8192];

  int bxi, byi, bzi; xcd_decode(bxi, byi, bzi);
  const int m0 = byi*256, n0 = bxi*256;
  if (CSK == 1 && n0 > m0 + 255) return;     // fully-masked causal block

  const int z = bzi, bb = z >> 3, hh = z & 7;
  A += (size_t)bb*aOffB + (size_t)hh*aOffH;
  B += (size_t)bb*bOffB + (size_t)hh*bOffH;
  const size_t coff = (size_t)bb*cOffB + (size_t)hh*cOffH;

  const int tid = threadIdx.x, lane = tid & 63, w = tid >> 6;
  const int wr = w >> 2, wc = w & 3;
  const int l15 = lane & 15, l4 = lane >> 4;

  int Keff = K;
  if (CSK == 2) Keff = (m0 + 256 < K) ? (m0 + 256) : K;
  const int nt = Keff >> 6;

  const int r8  = tid >> 3;                  // 0..63
  const int sc8 = ((tid & 7) ^ (r8 & 7)) * 8;

  auto stageA = [&](int buf, int half, int kt){
    #pragma unroll
    for (int j = 0; j < 2; j++){
      const int lr = j*64 + r8;              // local row 0..127
      gload16(A + (size_t)(m0 + half*128 + lr)*lda + kt + sc8,
              &Ab[buf][half][j*4096 + tid*8]);
    }
  };
  auto stageB = [&](int buf, int half, int kt){
    #pragma unroll
    for (int j = 0; j < 2; j++){
      const int lr = j*64 + r8;
      gload16(B + (size_t)(n0 + half*128 + lr)*ldb + kt + sc8,
              &Bb[buf][half][j*4096 + tid*8]);
    }
  };

  f32x4 acc[8][4] = {};

  // prologue: B0h0,B0h1,A0h0,A0h1,[A1h0,A1h1,B1h0,B1h1]  (issue order matters)
  stageB(0,0,0); stageB(0,1,0);
  stageA(0,0,0); stageA(0,1,0);
  if (nt > 1){
    stageA(1,0,64); stageA(1,1,64);
    stageB(1,0,64); stageB(1,1,64);
    asm volatile("s_waitcnt vmcnt(8)" ::: "memory");   // tile 0 certified
  } else {
    asm volatile("s_waitcnt vmcnt(0)" ::: "memory");
  }
  __builtin_amdgcn_s_barrier();
  __builtin_amdgcn_sched_barrier(0);

  for (int Q = 0; Q < nt; Q++){
    const int cur = Q & 1;
    if (Q > 0){
      if (Q + 1 < nt) asm volatile("s_waitcnt vmcnt(4)" ::: "memory");
      else            asm volatile("s_waitcnt vmcnt(0)" ::: "memory");
      __builtin_amdgcn_s_barrier();
      __builtin_amdgcn_sched_barrier(0);
    }
    bf16x8 bfr[4][2];
    #pragma unroll
    for (int s = 0; s < 4; s++){
      if (s == 0){
        #pragma unroll
        for (int fc = 0; fc < 4; fc++){
          const int R = wc*64 + fc*16 + l15;
          const int hb = R >> 7, lr = R & 127;
          #pragma unroll
          for (int kc = 0; kc < 2; kc++){
            const int cc = (kc*32 + l4*8) ^ ((lr & 7) * 8);
            bfr[fc][kc] = *(const bf16x8*)&Bb[cur][hb][lr*64 + cc];
          }
        }
      }
      bf16x8 ar[2][2];
      #pragma unroll
      for (int f = 0; f < 2; f++){
        const int lr = (s*2 + f)*16 + l15;
        #pragma unroll
        for (int kc = 0; kc < 2; kc++){
          const int cc = (kc*32 + l4*8) ^ ((lr & 7) * 8);
          ar[f][kc] = *(const bf16x8*)&Ab[cur][wr][lr*64 + cc];
        }
      }
      // this sub's half-tile stage
      if (s == 0 && Q >= 1 && Q + 1 < nt) stageA(cur ^ 1, 0, (Q+1)*64);
      if (s == 1 && Q >= 1 && Q + 1 < nt) stageA(cur ^ 1, 1, (Q+1)*64);
      if (s == 2 && Q + 2 < nt)           stageB(cur,     0, (Q+2)*64);
      if (s == 3 && Q + 2 < nt)           stageB(cur,     1, (Q+2)*64);

      asm volatile("s_waitcnt lgkmcnt(0)" ::: "memory");
      __builtin_amdgcn_sched_barrier(0);
      __builtin_amdgcn_s_setprio(1);
      #pragma unroll
      for (int f = 0; f < 2; f++)
        #pragma unroll
        for (int fc = 0; fc < 4; fc++)
          #pragma unroll
          for (int kc = 0; kc < 2; kc++)
            acc[s*2+f][fc] = __builtin_amdgcn_mfma_f32_16x16x32_bf16(
                ar[f][kc], bfr[fc][kc], acc[s*2+f][fc], 0, 0, 0);
      __builtin_amdgcn_s_setprio(0);
      __builtin_amdgcn_s_barrier();
      __builtin_amdgcn_sched_barrier(0);
    }
  }

  #pragma unroll
  for (int fr = 0; fr < 8; fr++){
    const int mb = m0 + wr*128 + fr*16 + l4*4;
    #pragma unroll
    for (int fc = 0; fc < 4; fc++){
      const int n = n0 + wc*64 + fc*16 + l15;
      const float bv = bias ? bias[n] : 0.0f;
      #pragma unroll
      for (int r = 0; r < 4; r++){
        const float v = acc[fr][fc][r] + bv;
        if (CMODE == 0) ((float*)C)[coff + (size_t)(mb + r)*ldc + n] = v;
        else            ((unsigned short*)C)[coff + (size_t)(mb + r)*ldc + n] = f2bf(v);
      }
    }
  }
}

// ---------------------------------------------------------------------------
// gemm_bt: 128x128 tile, BK=64, 4 waves, 2-phase dbuf (ff1 only).
// CMODE: 0=f32, 1=bf16, 2=bf16 gelu.
// ---------------------------------------------------------------------------
template<int CMODE>
__global__ __launch_bounds__(256, 2)
void gemm_bt(const unsigned short* __restrict__ A, const unsigned short* __restrict__ B,
             void* __restrict__ C, const float* __restrict__ bias,
             int M, int N, int K, int lda, int ldb, int ldc)
{
  __shared__ unsigned short Ab[2][8192];
  __shared__ unsigned short Bb[2][8192];

  int bxi, byi, bzi; xcd_decode(bxi, byi, bzi);
  (void)bzi;
  const int m0 = byi*128, n0 = bxi*128;

  const int tid = threadIdx.x, lane = tid & 63, w = tid >> 6;
  const int wr = w >> 1, wc = w & 1;
  const int l15 = lane & 15, l4 = lane >> 4;
  const int nt = K >> 6;

  const int r8  = tid >> 3;
  const int sc8 = ((tid & 7) ^ (r8 & 7)) * 8;

  auto stage = [&](int buf, int kt){
    #pragma unroll
    for (int j = 0; j < 4; j++){
      gload16(A + (size_t)(m0 + j*32 + r8)*lda + kt + sc8, &Ab[buf][j*2048 + tid*8]);
      gload16(B + (size_t)(n0 + j*32 + r8)*ldb + kt + sc8, &Bb[buf][j*2048 + tid*8]);
    }
  };

  f32x4 acc[4][4] = {};

  stage(0, 0);
  __syncthreads();
  for (int t = 0; t < nt; t++){
    const int cur = t & 1;
    if (t + 1 < nt) stage(cur ^ 1, (t+1)*64);

    bf16x8 af[4][2], bfr[4][2];
    #pragma unroll
    for (int i = 0; i < 4; i++){
      const int Ra = wr*64 + i*16 + l15;
      const int Rb = wc*64 + i*16 + l15;
      #pragma unroll
      for (int kc = 0; kc < 2; kc++){
        const int ca = (kc*32 + l4*8) ^ ((Ra & 7) * 8);
        const int cb = (kc*32 + l4*8) ^ ((Rb & 7) * 8);
        af[i][kc]  = *(const bf16x8*)&Ab[cur][Ra*64 + ca];
        bfr[i][kc] = *(const bf16x8*)&Bb[cur][Rb*64 + cb];
      }
    }
    #pragma unroll
    for (int i = 0; i < 4; i++)
      #pragma unroll
      for (int jj = 0; jj < 4; jj++)
        #pragma unroll
        for (int kc = 0; kc < 2; kc++)
          acc[i][jj] = __builtin_amdgcn_mfma_f32_16x16x32_bf16(
              af[i][kc], bfr[jj][kc], acc[i][jj], 0, 0, 0);
    __syncthreads();
  }

  #pragma unroll
  for (int i = 0; i < 4; i++){
    const int mbase = m0 + wr*64 + i*16 + l4*4;
    #pragma unroll
    for (int jj = 0; jj < 4; jj++){
      const int n = n0 + wc*64 + jj*16 + l15;
      const float bv = bias ? bias[n] : 0.0f;
      #pragma unroll
      for (int r = 0; r < 4; r++){
        const int m = mbase + r;
        float v = acc[i][jj][r] + bv;
        if (CMODE == 0){
          ((float*)C)[(size_t)m*ldc + n] = v;
        } else if (CMODE == 1){
          ((unsigned short*)C)[(size_t)m*ldc + n] = f2bf(v);
        } else {
          v = 0.5f * v * (1.0f + erff(v * 0.70710678118654752f));   // exact GELU
          ((unsigned short*)C)[(size_t)m*ldc + n] = f2bf(v);
        }
      }
    }
  }
}

// ---------------------------------------------------------------------------
template<int CAUSAL>
__global__ __launch_bounds__(256)
void softmax_rows(float* __restrict__ scores)
{
  const int row  = blockIdx.x*4 + (threadIdx.x >> 6);
  const int lane = threadIdx.x & 63;
  const int q = row & 511;
  const float* srow = scores + (size_t)row*512;
  float s[8]; float m = -1e30f;
  #pragma unroll
  for (int i = 0; i < 8; i++){
    const int col = lane*8 + i;
    float v = srow[col] * 0.044194173824159216f;   // 1/sqrt(512)
    if (CAUSAL && col > q) v = -1e30f;
    s[i] = v; m = fmaxf(m, v);
  }
  #pragma unroll
  for (int o = 32; o; o >>= 1) m = fmaxf(m, __shfl_xor(m, o));
  float p[8], sum = 0.f;
  #pragma unroll
  for (int i = 0; i < 8; i++){
    float e = __expf(s[i] - m);
    if (CAUSAL && (lane*8 + i) > q) e = 0.f;
    p[i] = e; sum += e;
  }
  #pragma unroll
  for (int o = 32; o; o >>= 1) sum += __shfl_xor(sum, o);
  const float inv = 1.0f / sum;
  unsigned short* prow = (unsigned short*)scores + (size_t)row*1024;
  #pragma unroll
  for (int i = 0; i < 8; i++) prow[lane*8 + i] = f2bf(p[i] * inv);
}

// ---------------------------------------------------------------------------
// y = LayerNorm(x + sum_{p<ND} partial_p + bias) * g + b.
// BFP=1: partials are bf16 (short8 vector loads); BFP=0: f32.
// ---------------------------------------------------------------------------
template<int WRITE_BF, int ND, int BFP>
__global__ __launch_bounds__(256)
void ln_rows(const float* __restrict__ x, const void* __restrict__ dbase,
             size_t dstride, const float* __restrict__ bias,
             const float* __restrict__ g, const float* __restrict__ bta,
             float* __restrict__ xo, unsigned short* __restrict__ xb)
{
  const int row = blockIdx.x*4 + (threadIdx.x >> 6);
  const int lane = threadIdx.x & 63;
  const float* xr = x + (size_t)row*512;
  float v[8];
  #pragma unroll
  for (int i = 0; i < 8; i++){
    const int c = lane*8 + i;
    v[i] = xr[c] + (bias ? bias[c] : 0.0f);
  }
  #pragma unroll
  for (int p = 0; p < ND; p++){
    if (BFP){
      const unsigned short* db = (const unsigned short*)dbase;
      u16x8 dv = *(const u16x8*)(db + p*dstride + (size_t)row*512 + lane*8);
      #pragma unroll
      for (int i = 0; i < 8; i++) v[i] += bf2f(dv[i]);
    } else {
      const float* db = (const float*)dbase;
      #pragma unroll
      for (int i = 0; i < 8; i++) v[i] += db[p*dstride + (size_t)row*512 + lane*8 + i];
    }
  }
  float sum = 0.f;
  #pragma unroll
  for (int i = 0; i < 8; i++) sum += v[i];
  #pragma unroll
  for (int o = 32; o; o >>= 1) sum += __shfl_xor(sum, o);
  const float mean = sum * (1.0f/512.0f);
  float s2 = 0.f;
  #pragma unroll
  for (int i = 0; i < 8; i++){ const float t = v[i] - mean; s2 += t*t; }
  #pragma unroll
  for (int o = 32; o; o >>= 1) s2 += __shfl_xor(s2, o);
  const float inv = rsqrtf(s2 * (1.0f/512.0f) + 1e-3f);
  #pragma unroll
  for (int i = 0; i < 8; i++){
    const int c = lane*8 + i;
    const float y = (v[i] - mean)*inv*g[c] + bta[c];
    xo[(size_t)row*512 + c] = y;
    if (WRITE_BF) xb[(size_t)row*512 + c] = f2bf(y);
  }
}

struct Cast2 { const float* s[2]; unsigned short* d[2]; };

__global__ __launch_bounds__(256)
void cast_bf16_k2(Cast2 a, int n)
{
  const int z = blockIdx.y;
  const int i = (blockIdx.x*256 + threadIdx.x)*4;
  if (i < n){
    const float4 v = *(const float4*)(a.s[z] + i);
    uint2 o;
    o.x = (unsigned)f2bf(v.x) | ((unsigned)f2bf(v.y) << 16);
    o.y = (unsigned)f2bf(v.z) | ((unsigned)f2bf(v.w) << 16);
    *(uint2*)(a.d[z] + i) = o;
  }
}

struct TC8 { const float* s[8]; unsigned short* d[8]; };

// src [R][C] f32 -> dst [C][R] bf16 ; z = blockIdx.z selects tensor
__global__ __launch_bounds__(256)
void transpose_cast8(TC8 a, int R, int C)
{
  __shared__ float tile[32][33];
  const int z = blockIdx.z;
  const float* src = a.s[z];
  unsigned short* dst = a.d[z];
  const int bx = blockIdx.x*32, by = blockIdx.y*32;
  const int tx = threadIdx.x & 31, ty = threadIdx.x >> 5;   // 256 thr = 32x8
  #pragma unroll
  for (int i = 0; i < 32; i += 8) tile[ty + i][tx] = src[(size_t)(by + ty + i)*C + bx + tx];
  __syncthreads();
  #pragma unroll
  for (int i = 0; i < 32; i += 8) dst[(size_t)(bx + ty + i)*R + by + tx] = f2bf(tile[tx][ty + i]);
}

// vb [4096 m=(b,s)][4096 n=(h,ko)] bf16  ->  vT [b][h][ko][s] bf16
__global__ __launch_bounds__(256)
void transpose_v(const unsigned short* __restrict__ src, unsigned short* __restrict__ dst)
{
  __shared__ unsigned short t[32][34];
  const int z = blockIdx.z, b = z >> 3, h = z & 7;
  const int s0 = blockIdx.y*32, k0 = blockIdx.x*32;
  const int tx = threadIdx.x & 31, ty4 = (threadIdx.x >> 5) * 4;
  #pragma unroll
  for (int i = 0; i < 4; i++)
    t[ty4 + i][tx] = src[(size_t)(b*512 + s0 + ty4 + i)*4096 + h*512 + k0 + tx];
  __syncthreads();
  unsigned short* d = dst + ((size_t)z*512 + k0)*512 + s0;
  #pragma unroll
  for (int i = 0; i < 4; i++)
    d[(size_t)(ty4 + i)*512 + tx] = t[tx][ty4 + i];
}

// ---------------------------------------------------------------------------
extern "C" void kernel_launch(void* const* d_in, const int* in_sizes, int n_in,
                              void* d_out, int out_size, void* d_ws, size_t ws_size,
                              hipStream_t stream)
{
  (void)in_sizes; (void)n_in; (void)out_size; (void)ws_size;

  const float* in_seq  = (const float*)d_in[0];
  const float* out_seq = (const float*)d_in[1];
  const float* sa_wq = (const float*)d_in[2];  const float* sa_bq = (const float*)d_in[3];
  const float* sa_wk = (const float*)d_in[4];  const float* sa_bk = (const float*)d_in[5];
  const float* sa_wv = (const float*)d_in[6];  const float* sa_bv = (const float*)d_in[7];
  const float* sa_wo = (const float*)d_in[8];  const float* sa_bo = (const float*)d_in[9];
  const float* sa_lng = (const float*)d_in[10]; const float* sa_lnb = (const float*)d_in[11];
  const float* ca_wq = (const float*)d_in[12]; const float* ca_bq = (const float*)d_in[13];
  const float* ca_wk = (const float*)d_in[14]; const float* ca_bk = (const float*)d_in[15];
  const float* ca_wv = (const float*)d_in[16]; const float* ca_bv = (const float*)d_in[17];
  const float* ca_wo = (const float*)d_in[18]; const float* ca_bo = (const float*)d_in[19];
  const float* ca_lng = (const float*)d_in[20]; const float* ca_lnb = (const float*)d_in[21];
  const float* ff_w1 = (const float*)d_in[22]; const float* ff_b1 = (const float*)d_in[23];
  const float* ff_w2 = (const float*)d_in[24]; const float* ff_b2 = (const float*)d_in[25];
  const float* ff_lng = (const float*)d_in[26]; const float* ff_lnb = (const float*)d_in[27];

  char* ws = (char*)d_ws;
  size_t off = 0;
  auto alloc = [&](size_t bytes){ char* p = ws + off; off += (bytes + 255) & ~(size_t)255; return p; };

  unsigned short* wT[8];
  for (int i = 0; i < 8; i++) wT[i] = (unsigned short*)alloc(4096ULL*512*2);
  unsigned short* w1T  = (unsigned short*)alloc(1024ULL*512*2);
  unsigned short* w2T  = (unsigned short*)alloc(512ULL*1024*2);
  unsigned short* xbf  = (unsigned short*)alloc(4096ULL*512*2);
  unsigned short* inbf = (unsigned short*)alloc(4096ULL*512*2);
  unsigned short* qb   = (unsigned short*)alloc(4096ULL*4096*2);   // also FFN hidden
  unsigned short* kb   = (unsigned short*)alloc(4096ULL*4096*2);   // also attn-out
  unsigned short* vT   = (unsigned short*)alloc(64ULL*512*512*2);
  float*          sc   = (float*)alloc(64ULL*512*512*4);           // 64 MB multi-use
  float*          xcur = (float*)alloc(4096ULL*512*4);

  // sc region timeline: vb (V-proj) -> transpose_v -> f32 scores -> bf16
  // probs in-place -> PV -> 8 bf16 split-K partial slices -> ln_rows.
  unsigned short* vb   = (unsigned short*)sc;
  unsigned short* part = (unsigned short*)sc;
  const size_t PART_STRIDE = 2097152;   // ushorts per slice (4096*512)

  // ---- prologue (merged) ----
  Cast2 c2{{out_seq, in_seq}, {xbf, inbf}};
  cast_bf16_k2<<<dim3(2048,2), 256, 0, stream>>>(c2, 4096*512);

  TC8 tqkv{{sa_wq, sa_wk, sa_wv, ca_wq, ca_wk, ca_wv, nullptr, nullptr},
           {wT[0], wT[1], wT[2], wT[4], wT[5], wT[6], nullptr, nullptr}};
  transpose_cast8<<<dim3(128,16,6), 256, 0, stream>>>(tqkv, 512, 4096);
  TC8 two{{sa_wo, ca_wo, nullptr,nullptr,nullptr,nullptr,nullptr,nullptr},
          {wT[3], wT[7], nullptr,nullptr,nullptr,nullptr,nullptr,nullptr}};
  transpose_cast8<<<dim3(16,128,2), 256, 0, stream>>>(two, 4096, 512);
  TC8 tw1{{ff_w1, nullptr,nullptr,nullptr,nullptr,nullptr,nullptr,nullptr},
          {w1T, nullptr,nullptr,nullptr,nullptr,nullptr,nullptr,nullptr}};
  transpose_cast8<<<dim3(32,16,1), 256, 0, stream>>>(tw1, 512, 1024);
  TC8 tw2{{ff_w2, nullptr,nullptr,nullptr,nullptr,nullptr,nullptr,nullptr},
          {w2T, nullptr,nullptr,nullptr,nullptr,nullptr,nullptr,nullptr}};
  transpose_cast8<<<dim3(16,32,1), 256, 0, stream>>>(tw2, 1024, 512);

  #define G256(MODE, CSK, Apt, Bpt, Cpt, BIAS, M, N, K, LDA, LDB, LDC, Z, aH, aB, bH, bB, cH, cB) \
    gemm256<MODE, CSK><<<dim3((N)/256,(M)/256,(Z)), 512, 0, stream>>>( \
      (const unsigned short*)(Apt), (const unsigned short*)(Bpt), (void*)(Cpt), BIAS, \
      M, N, K, LDA, LDB, LDC, aH, aB, bH, bB, cH, cB)

  // ---- self-attention (causal) ----
  Proj3 saP{{xbf, xbf, xbf}, {wT[0], wT[1], wT[2]}, {qb, kb, vb}, {sa_bq, sa_bk, sa_bv}};
  qkv256<<<dim3(16,16,3), 512, 0, stream>>>(saP);
  transpose_v<<<dim3(16,16,64), 256, 0, stream>>>(vb, vT);
  G256(0, 1, qb, kb, sc, nullptr, 512, 512, 512, 4096, 4096, 512, 64,
       512, 2097152, 512, 2097152, 262144, 2097152);
  softmax_rows<1><<<8192, 256, 0, stream>>>(sc);
  G256(1, 2, sc, vT, kb, nullptr, 512, 512, 512, 1024, 512, 4096, 64,
       524288, 4194304, 262144, 2097152, 512, 2097152);
  G256(1, 0, kb, wT[3], part, nullptr, 4096, 512, 512, 4096, 4096, 512, 8,
       512, 0, 512, 0, PART_STRIDE, 0);
  ln_rows<1, 8, 1><<<1024, 256, 0, stream>>>(out_seq, part, PART_STRIDE,
                                             sa_bo, sa_lng, sa_lnb, xcur, xbf);

  // ---- cross-attention ----
  Proj3 caP{{xbf, inbf, inbf}, {wT[4], wT[5], wT[6]}, {qb, kb, vb}, {ca_bq, ca_bk, ca_bv}};
  qkv256<<<dim3(16,16,3), 512, 0, stream>>>(caP);
  transpose_v<<<dim3(16,16,64), 256, 0, stream>>>(vb, vT);
  G256(0, 0, qb, kb, sc, nullptr, 512, 512, 512, 4096, 4096, 512, 64,
       512, 2097152, 512, 2097152, 262144, 2097152);
  softmax_rows<0><<<8192, 256, 0, stream>>>(sc);
  G256(1, 0, sc, vT, kb, nullptr, 512, 512, 512, 1024, 512, 4096, 64,
       524288, 4194304, 262144, 2097152, 512, 2097152);
  G256(1, 0, kb, wT[7], part, nullptr, 4096, 512, 512, 4096, 4096, 512, 8,
       512, 0, 512, 0, PART_STRIDE, 0);
  ln_rows<1, 8, 1><<<1024, 256, 0, stream>>>(xcur, part, PART_STRIDE,
                                             ca_bo, ca_lng, ca_lnb, xcur, xbf);

  // ---- FFN ----
  gemm_bt<2><<<dim3(8,32,1), 256, 0, stream>>>(
      xbf, w1T, (void*)qb, ff_b1, 4096, 1024, 512, 512, 512, 1024);
  G256(1, 0, qb, w2T, part, nullptr, 4096, 512, 128, 1024, 1024, 512, 8,
       128, 0, 128, 0, PART_STRIDE, 0);
  ln_rows<0, 8, 1><<<1024, 256, 0, stream>>>(xcur, part, PART_STRIDE,
                                             ff_b2, ff_lng, ff_lnb, (float*)d_out, nullptr);

  #undef G256
}

// Round 16
// 490.030 us; speedup vs baseline: 1.1792x; 1.0178x over previous
//
#include <hip/hip_runtime.h>
#include <math.h>

#define DEV __device__ __forceinline__

typedef __bf16 bf16x8 __attribute__((ext_vector_type(8)));
typedef float f32x4 __attribute__((ext_vector_type(4)));
typedef unsigned short u16x8 __attribute__((ext_vector_type(8)));

typedef const __attribute__((address_space(1))) void gv_t;
typedef __attribute__((address_space(3))) void lv_t;

DEV unsigned short f2bf(float f){
  unsigned int u = __float_as_uint(f);
  u += 0x7fffu + ((u >> 16) & 1u);     // round-to-nearest-even
  return (unsigned short)(u >> 16);
}
DEV float bf2f(unsigned short u){ return __uint_as_float((unsigned)u << 16); }

DEV void gload16(const void* g, void* l){
  __builtin_amdgcn_global_load_lds((gv_t*)g, (lv_t*)l, 16, 0, 0);
}

// T1 chunked XCD swizzle (bijective when nwg%8==0, identity otherwise).
DEV void xcd_decode(int& bx, int& by, int& bz){
  const int gx = gridDim.x, gy = gridDim.y;
  const int nwg = gx * gy * gridDim.z;
  int lin = blockIdx.x + gx*(blockIdx.y + gy*blockIdx.z);
  if ((nwg & 7) == 0) lin = (lin & 7)*(nwg >> 3) + (lin >> 3);
  bx = lin % gx; const int t = lin / gx;
  by = t % gy;  bz = t / gy;
}

struct Proj3 {
  const unsigned short* A[3];
  const unsigned short* B[3];
  unsigned short*       C[3];
  const float*          bias[3];
};

// ---------------------------------------------------------------------------
// qkv256 (NEW schedule): three 4096x4096x512 projections in one dispatch.
// Same verified counted-vmcnt half-tile schedule as gemm256 (R15): per K-tile
// quad of 4 subs {ds_read frags, issue ONE half stage, lgkmcnt(0)+SB,
// setprio(1), 16 MFMA, setprio(0), s_barrier}; vmcnt(8) prologue, vmcnt(4)
// steady, vmcnt(0) final.  Fixed lda=ldb=512, ldc=4096, nt=8, bf16+bias.
// ---------------------------------------------------------------------------
__global__ __launch_bounds__(512, 2)
void qkv256(Proj3 pr)
{
  __shared__ unsigned short Ab[2][2][8192];   // [buf][half][128*64]
  __shared__ unsigned short Bb[2][2][8192];

  int bxi, byi, bzi; xcd_decode(bxi, byi, bzi);
  const int m0 = byi*256, n0 = bxi*256;
  const unsigned short* A = pr.A[bzi];
  const unsigned short* B = pr.B[bzi];
  unsigned short*       C = pr.C[bzi];
  const float*       bias = pr.bias[bzi];

  const int tid = threadIdx.x, lane = tid & 63, w = tid >> 6;
  const int wr = w >> 2, wc = w & 3;
  const int l15 = lane & 15, l4 = lane >> 4;

  const int r8  = tid >> 3;
  const int sc8 = ((tid & 7) ^ (r8 & 7)) * 8;

  auto stageA = [&](int buf, int half, int kt){
    #pragma unroll
    for (int j = 0; j < 2; j++){
      const int lr = j*64 + r8;
      gload16(A + (size_t)(m0 + half*128 + lr)*512 + kt + sc8,
              &Ab[buf][half][j*4096 + tid*8]);
    }
  };
  auto stageB = [&](int buf, int half, int kt){
    #pragma unroll
    for (int j = 0; j < 2; j++){
      const int lr = j*64 + r8;
      gload16(B + (size_t)(n0 + half*128 + lr)*512 + kt + sc8,
              &Bb[buf][half][j*4096 + tid*8]);
    }
  };

  f32x4 acc[8][4] = {};

  stageB(0,0,0); stageB(0,1,0);
  stageA(0,0,0); stageA(0,1,0);
  stageA(1,0,64); stageA(1,1,64);
  stageB(1,0,64); stageB(1,1,64);
  asm volatile("s_waitcnt vmcnt(8)" ::: "memory");
  __builtin_amdgcn_s_barrier();
  __builtin_amdgcn_sched_barrier(0);

  const int nt = 8;
  for (int Q = 0; Q < nt; Q++){
    const int cur = Q & 1;
    if (Q > 0){
      if (Q + 1 < nt) asm volatile("s_waitcnt vmcnt(4)" ::: "memory");
      else            asm volatile("s_waitcnt vmcnt(0)" ::: "memory");
      __builtin_amdgcn_s_barrier();
      __builtin_amdgcn_sched_barrier(0);
    }
    bf16x8 bfr[4][2];
    #pragma unroll
    for (int s = 0; s < 4; s++){
      if (s == 0){
        #pragma unroll
        for (int fc = 0; fc < 4; fc++){
          const int R = wc*64 + fc*16 + l15;
          const int hb = R >> 7, lr = R & 127;
          #pragma unroll
          for (int kc = 0; kc < 2; kc++){
            const int cc = (kc*32 + l4*8) ^ ((lr & 7) * 8);
            bfr[fc][kc] = *(const bf16x8*)&Bb[cur][hb][lr*64 + cc];
          }
        }
      }
      bf16x8 ar[2][2];
      #pragma unroll
      for (int f = 0; f < 2; f++){
        const int lr = (s*2 + f)*16 + l15;
        #pragma unroll
        for (int kc = 0; kc < 2; kc++){
          const int cc = (kc*32 + l4*8) ^ ((lr & 7) * 8);
          ar[f][kc] = *(const bf16x8*)&Ab[cur][wr][lr*64 + cc];
        }
      }
      if (s == 0 && Q >= 1 && Q + 1 < nt) stageA(cur ^ 1, 0, (Q+1)*64);
      if (s == 1 && Q >= 1 && Q + 1 < nt) stageA(cur ^ 1, 1, (Q+1)*64);
      if (s == 2 && Q + 2 < nt)           stageB(cur,     0, (Q+2)*64);
      if (s == 3 && Q + 2 < nt)           stageB(cur,     1, (Q+2)*64);

      asm volatile("s_waitcnt lgkmcnt(0)" ::: "memory");
      __builtin_amdgcn_sched_barrier(0);
      __builtin_amdgcn_s_setprio(1);
      #pragma unroll
      for (int f = 0; f < 2; f++)
        #pragma unroll
        for (int fc = 0; fc < 4; fc++)
          #pragma unroll
          for (int kc = 0; kc < 2; kc++)
            acc[s*2+f][fc] = __builtin_amdgcn_mfma_f32_16x16x32_bf16(
                ar[f][kc], bfr[fc][kc], acc[s*2+f][fc], 0, 0, 0);
      __builtin_amdgcn_s_setprio(0);
      __builtin_amdgcn_s_barrier();
      __builtin_amdgcn_sched_barrier(0);
    }
  }

  #pragma unroll
  for (int fr = 0; fr < 8; fr++){
    const int mb = m0 + wr*128 + fr*16 + l4*4;
    #pragma unroll
    for (int fc = 0; fc < 4; fc++){
      const int n = n0 + wc*64 + fc*16 + l15;
      const float bv = bias[n];
      #pragma unroll
      for (int r = 0; r < 4; r++)
        C[(size_t)(mb + r)*4096 + n] = f2bf(acc[fr][fc][r] + bv);
    }
  }
}

// ---------------------------------------------------------------------------
// gemm256: counted-vmcnt half-tile schedule (verified R15).
// CMODE: 0=f32, 1=bf16. CSK: 0 none, 1 causal block-skip, 2 causal K-clamp.
// ---------------------------------------------------------------------------
template<int CMODE, int CSK>
__global__ __launch_bounds__(512, 2)
void gemm256(const unsigned short* __restrict__ A, const unsigned short* __restrict__ B,
             void* __restrict__ C, const float* __restrict__ bias,
             int M, int N, int K, int lda, int ldb, int ldc,
             size_t aOffH, size_t aOffB, size_t bOffH, size_t bOffB,
             size_t cOffH, size_t cOffB)
{
  __shared__ unsigned short Ab[2][2][8192];   // [buf][half][128*64]
  __shared__ unsigned short Bb[2][2][8192];

  int bxi, byi, bzi; xcd_decode(bxi, byi, bzi);
  const int m0 = byi*256, n0 = bxi*256;
  if (CSK == 1 && n0 > m0 + 255) return;     // fully-masked causal block

  const int z = bzi, bb = z >> 3, hh = z & 7;
  A += (size_t)bb*aOffB + (size_t)hh*aOffH;
  B += (size_t)bb*bOffB + (size_t)hh*bOffH;
  const size_t coff = (size_t)bb*cOffB + (size_t)hh*cOffH;

  const int tid = threadIdx.x, lane = tid & 63, w = tid >> 6;
  const int wr = w >> 2, wc = w & 3;
  const int l15 = lane & 15, l4 = lane >> 4;

  int Keff = K;
  if (CSK == 2) Keff = (m0 + 256 < K) ? (m0 + 256) : K;
  const int nt = Keff >> 6;

  const int r8  = tid >> 3;
  const int sc8 = ((tid & 7) ^ (r8 & 7)) * 8;

  auto stageA = [&](int buf, int half, int kt){
    #pragma unroll
    for (int j = 0; j < 2; j++){
      const int lr = j*64 + r8;
      gload16(A + (size_t)(m0 + half*128 + lr)*lda + kt + sc8,
              &Ab[buf][half][j*4096 + tid*8]);
    }
  };
  auto stageB = [&](int buf, int half, int kt){
    #pragma unroll
    for (int j = 0; j < 2; j++){
      const int lr = j*64 + r8;
      gload16(B + (size_t)(n0 + half*128 + lr)*ldb + kt + sc8,
              &Bb[buf][half][j*4096 + tid*8]);
    }
  };

  f32x4 acc[8][4] = {};

  stageB(0,0,0); stageB(0,1,0);
  stageA(0,0,0); stageA(0,1,0);
  if (nt > 1){
    stageA(1,0,64); stageA(1,1,64);
    stageB(1,0,64); stageB(1,1,64);
    asm volatile("s_waitcnt vmcnt(8)" ::: "memory");
  } else {
    asm volatile("s_waitcnt vmcnt(0)" ::: "memory");
  }
  __builtin_amdgcn_s_barrier();
  __builtin_amdgcn_sched_barrier(0);

  for (int Q = 0; Q < nt; Q++){
    const int cur = Q & 1;
    if (Q > 0){
      if (Q + 1 < nt) asm volatile("s_waitcnt vmcnt(4)" ::: "memory");
      else            asm volatile("s_waitcnt vmcnt(0)" ::: "memory");
      __builtin_amdgcn_s_barrier();
      __builtin_amdgcn_sched_barrier(0);
    }
    bf16x8 bfr[4][2];
    #pragma unroll
    for (int s = 0; s < 4; s++){
      if (s == 0){
        #pragma unroll
        for (int fc = 0; fc < 4; fc++){
          const int R = wc*64 + fc*16 + l15;
          const int hb = R >> 7, lr = R & 127;
          #pragma unroll
          for (int kc = 0; kc < 2; kc++){
            const int cc = (kc*32 + l4*8) ^ ((lr & 7) * 8);
            bfr[fc][kc] = *(const bf16x8*)&Bb[cur][hb][lr*64 + cc];
          }
        }
      }
      bf16x8 ar[2][2];
      #pragma unroll
      for (int f = 0; f < 2; f++){
        const int lr = (s*2 + f)*16 + l15;
        #pragma unroll
        for (int kc = 0; kc < 2; kc++){
          const int cc = (kc*32 + l4*8) ^ ((lr & 7) * 8);
          ar[f][kc] = *(const bf16x8*)&Ab[cur][wr][lr*64 + cc];
        }
      }
      if (s == 0 && Q >= 1 && Q + 1 < nt) stageA(cur ^ 1, 0, (Q+1)*64);
      if (s == 1 && Q >= 1 && Q + 1 < nt) stageA(cur ^ 1, 1, (Q+1)*64);
      if (s == 2 && Q + 2 < nt)           stageB(cur,     0, (Q+2)*64);
      if (s == 3 && Q + 2 < nt)           stageB(cur,     1, (Q+2)*64);

      asm volatile("s_waitcnt lgkmcnt(0)" ::: "memory");
      __builtin_amdgcn_sched_barrier(0);
      __builtin_amdgcn_s_setprio(1);
      #pragma unroll
      for (int f = 0; f < 2; f++)
        #pragma unroll
        for (int fc = 0; fc < 4; fc++)
          #pragma unroll
          for (int kc = 0; kc < 2; kc++)
            acc[s*2+f][fc] = __builtin_amdgcn_mfma_f32_16x16x32_bf16(
                ar[f][kc], bfr[fc][kc], acc[s*2+f][fc], 0, 0, 0);
      __builtin_amdgcn_s_setprio(0);
      __builtin_amdgcn_s_barrier();
      __builtin_amdgcn_sched_barrier(0);
    }
  }

  #pragma unroll
  for (int fr = 0; fr < 8; fr++){
    const int mb = m0 + wr*128 + fr*16 + l4*4;
    #pragma unroll
    for (int fc = 0; fc < 4; fc++){
      const int n = n0 + wc*64 + fc*16 + l15;
      const float bv = bias ? bias[n] : 0.0f;
      #pragma unroll
      for (int r = 0; r < 4; r++){
        const float v = acc[fr][fc][r] + bv;
        if (CMODE == 0) ((float*)C)[coff + (size_t)(mb + r)*ldc + n] = v;
        else            ((unsigned short*)C)[coff + (size_t)(mb + r)*ldc + n] = f2bf(v);
      }
    }
  }
}

// ---------------------------------------------------------------------------
// gemm_bt: 128x128 tile, BK=64, 4 waves, 2-phase dbuf (ff1 only).
// CMODE: 0=f32, 1=bf16, 2=bf16 gelu.
// ---------------------------------------------------------------------------
template<int CMODE>
__global__ __launch_bounds__(256, 2)
void gemm_bt(const unsigned short* __restrict__ A, const unsigned short* __restrict__ B,
             void* __restrict__ C, const float* __restrict__ bias,
             int M, int N, int K, int lda, int ldb, int ldc)
{
  __shared__ unsigned short Ab[2][8192];
  __shared__ unsigned short Bb[2][8192];

  int bxi, byi, bzi; xcd_decode(bxi, byi, bzi);
  (void)bzi;
  const int m0 = byi*128, n0 = bxi*128;

  const int tid = threadIdx.x, lane = tid & 63, w = tid >> 6;
  const int wr = w >> 1, wc = w & 1;
  const int l15 = lane & 15, l4 = lane >> 4;
  const int nt = K >> 6;

  const int r8  = tid >> 3;
  const int sc8 = ((tid & 7) ^ (r8 & 7)) * 8;

  auto stage = [&](int buf, int kt){
    #pragma unroll
    for (int j = 0; j < 4; j++){
      gload16(A + (size_t)(m0 + j*32 + r8)*lda + kt + sc8, &Ab[buf][j*2048 + tid*8]);
      gload16(B + (size_t)(n0 + j*32 + r8)*ldb + kt + sc8, &Bb[buf][j*2048 + tid*8]);
    }
  };

  f32x4 acc[4][4] = {};

  stage(0, 0);
  __syncthreads();
  for (int t = 0; t < nt; t++){
    const int cur = t & 1;
    if (t + 1 < nt) stage(cur ^ 1, (t+1)*64);

    bf16x8 af[4][2], bfr[4][2];
    #pragma unroll
    for (int i = 0; i < 4; i++){
      const int Ra = wr*64 + i*16 + l15;
      const int Rb = wc*64 + i*16 + l15;
      #pragma unroll
      for (int kc = 0; kc < 2; kc++){
        const int ca = (kc*32 + l4*8) ^ ((Ra & 7) * 8);
        const int cb = (kc*32 + l4*8) ^ ((Rb & 7) * 8);
        af[i][kc]  = *(const bf16x8*)&Ab[cur][Ra*64 + ca];
        bfr[i][kc] = *(const bf16x8*)&Bb[cur][Rb*64 + cb];
      }
    }
    #pragma unroll
    for (int i = 0; i < 4; i++)
      #pragma unroll
      for (int jj = 0; jj < 4; jj++)
        #pragma unroll
        for (int kc = 0; kc < 2; kc++)
          acc[i][jj] = __builtin_amdgcn_mfma_f32_16x16x32_bf16(
              af[i][kc], bfr[jj][kc], acc[i][jj], 0, 0, 0);
    __syncthreads();
  }

  #pragma unroll
  for (int i = 0; i < 4; i++){
    const int mbase = m0 + wr*64 + i*16 + l4*4;
    #pragma unroll
    for (int jj = 0; jj < 4; jj++){
      const int n = n0 + wc*64 + jj*16 + l15;
      const float bv = bias ? bias[n] : 0.0f;
      #pragma unroll
      for (int r = 0; r < 4; r++){
        const int m = mbase + r;
        float v = acc[i][jj][r] + bv;
        if (CMODE == 0){
          ((float*)C)[(size_t)m*ldc + n] = v;
        } else if (CMODE == 1){
          ((unsigned short*)C)[(size_t)m*ldc + n] = f2bf(v);
        } else {
          v = 0.5f * v * (1.0f + erff(v * 0.70710678118654752f));   // exact GELU
          ((unsigned short*)C)[(size_t)m*ldc + n] = f2bf(v);
        }
      }
    }
  }
}

// ---------------------------------------------------------------------------
template<int CAUSAL>
__global__ __launch_bounds__(256)
void softmax_rows(float* __restrict__ scores)
{
  const int row  = blockIdx.x*4 + (threadIdx.x >> 6);
  const int lane = threadIdx.x & 63;
  const int q = row & 511;
  const float* srow = scores + (size_t)row*512;
  float s[8]; float m = -1e30f;
  #pragma unroll
  for (int i = 0; i < 8; i++){
    const int col = lane*8 + i;
    float v = srow[col] * 0.044194173824159216f;   // 1/sqrt(512)
    if (CAUSAL && col > q) v = -1e30f;
    s[i] = v; m = fmaxf(m, v);
  }
  #pragma unroll
  for (int o = 32; o; o >>= 1) m = fmaxf(m, __shfl_xor(m, o));
  float p[8], sum = 0.f;
  #pragma unroll
  for (int i = 0; i < 8; i++){
    float e = __expf(s[i] - m);
    if (CAUSAL && (lane*8 + i) > q) e = 0.f;
    p[i] = e; sum += e;
  }
  #pragma unroll
  for (int o = 32; o; o >>= 1) sum += __shfl_xor(sum, o);
  const float inv = 1.0f / sum;
  unsigned short* prow = (unsigned short*)scores + (size_t)row*1024;
  #pragma unroll
  for (int i = 0; i < 8; i++) prow[lane*8 + i] = f2bf(p[i] * inv);
}

// ---------------------------------------------------------------------------
// y = LayerNorm(x + sum_{p<ND} partial_p + bias) * g + b.
// BFP=1: partials are bf16 (short8 vector loads); BFP=0: f32.
// ---------------------------------------------------------------------------
template<int WRITE_BF, int ND, int BFP>
__global__ __launch_bounds__(256)
void ln_rows(const float* __restrict__ x, const void* __restrict__ dbase,
             size_t dstride, const float* __restrict__ bias,
             const float* __restrict__ g, const float* __restrict__ bta,
             float* __restrict__ xo, unsigned short* __restrict__ xb)
{
  const int row = blockIdx.x*4 + (threadIdx.x >> 6);
  const int lane = threadIdx.x & 63;
  const float* xr = x + (size_t)row*512;
  float v[8];
  #pragma unroll
  for (int i = 0; i < 8; i++){
    const int c = lane*8 + i;
    v[i] = xr[c] + (bias ? bias[c] : 0.0f);
  }
  #pragma unroll
  for (int p = 0; p < ND; p++){
    if (BFP){
      const unsigned short* db = (const unsigned short*)dbase;
      u16x8 dv = *(const u16x8*)(db + p*dstride + (size_t)row*512 + lane*8);
      #pragma unroll
      for (int i = 0; i < 8; i++) v[i] += bf2f(dv[i]);
    } else {
      const float* db = (const float*)dbase;
      #pragma unroll
      for (int i = 0; i < 8; i++) v[i] += db[p*dstride + (size_t)row*512 + lane*8 + i];
    }
  }
  float sum = 0.f;
  #pragma unroll
  for (int i = 0; i < 8; i++) sum += v[i];
  #pragma unroll
  for (int o = 32; o; o >>= 1) sum += __shfl_xor(sum, o);
  const float mean = sum * (1.0f/512.0f);
  float s2 = 0.f;
  #pragma unroll
  for (int i = 0; i < 8; i++){ const float t = v[i] - mean; s2 += t*t; }
  #pragma unroll
  for (int o = 32; o; o >>= 1) s2 += __shfl_xor(s2, o);
  const float inv = rsqrtf(s2 * (1.0f/512.0f) + 1e-3f);
  #pragma unroll
  for (int i = 0; i < 8; i++){
    const int c = lane*8 + i;
    const float y = (v[i] - mean)*inv*g[c] + bta[c];
    xo[(size_t)row*512 + c] = y;
    if (WRITE_BF) xb[(size_t)row*512 + c] = f2bf(y);
  }
}

struct Cast2 { const float* s[2]; unsigned short* d[2]; };

__global__ __launch_bounds__(256)
void cast_bf16_k2(Cast2 a, int n)
{
  const int z = blockIdx.y;
  const int i = (blockIdx.x*256 + threadIdx.x)*4;
  if (i < n){
    const float4 v = *(const float4*)(a.s[z] + i);
    uint2 o;
    o.x = (unsigned)f2bf(v.x) | ((unsigned)f2bf(v.y) << 16);
    o.y = (unsigned)f2bf(v.z) | ((unsigned)f2bf(v.w) << 16);
    *(uint2*)(a.d[z] + i) = o;
  }
}

struct TC8 { const float* s[8]; unsigned short* d[8]; };

// src [R][C] f32 -> dst [C][R] bf16 ; z = blockIdx.z selects tensor
__global__ __launch_bounds__(256)
void transpose_cast8(TC8 a, int R, int C)
{
  __shared__ float tile[32][33];
  const int z = blockIdx.z;
  const float* src = a.s[z];
  unsigned short* dst = a.d[z];
  const int bx = blockIdx.x*32, by = blockIdx.y*32;
  const int tx = threadIdx.x & 31, ty = threadIdx.x >> 5;   // 256 thr = 32x8
  #pragma unroll
  for (int i = 0; i < 32; i += 8) tile[ty + i][tx] = src[(size_t)(by + ty + i)*C + bx + tx];
  __syncthreads();
  #pragma unroll
  for (int i = 0; i < 32; i += 8) dst[(size_t)(bx + ty + i)*R + by + tx] = f2bf(tile[tx][ty + i]);
}

// vb [4096 m=(b,s)][4096 n=(h,ko)] bf16  ->  vT [b][h][ko][s] bf16
__global__ __launch_bounds__(256)
void transpose_v(const unsigned short* __restrict__ src, unsigned short* __restrict__ dst)
{
  __shared__ unsigned short t[32][34];
  const int z = blockIdx.z, b = z >> 3, h = z & 7;
  const int s0 = blockIdx.y*32, k0 = blockIdx.x*32;
  const int tx = threadIdx.x & 31, ty4 = (threadIdx.x >> 5) * 4;
  #pragma unroll
  for (int i = 0; i < 4; i++)
    t[ty4 + i][tx] = src[(size_t)(b*512 + s0 + ty4 + i)*4096 + h*512 + k0 + tx];
  __syncthreads();
  unsigned short* d = dst + ((size_t)z*512 + k0)*512 + s0;
  #pragma unroll
  for (int i = 0; i < 4; i++)
    d[(size_t)(ty4 + i)*512 + tx] = t[tx][ty4 + i];
}

// ---------------------------------------------------------------------------
extern "C" void kernel_launch(void* const* d_in, const int* in_sizes, int n_in,
                              void* d_out, int out_size, void* d_ws, size_t ws_size,
                              hipStream_t stream)
{
  (void)in_sizes; (void)n_in; (void)out_size; (void)ws_size;

  const float* in_seq  = (const float*)d_in[0];
  const float* out_seq = (const float*)d_in[1];
  const float* sa_wq = (const float*)d_in[2];  const float* sa_bq = (const float*)d_in[3];
  const float* sa_wk = (const float*)d_in[4];  const float* sa_bk = (const float*)d_in[5];
  const float* sa_wv = (const float*)d_in[6];  const float* sa_bv = (const float*)d_in[7];
  const float* sa_wo = (const float*)d_in[8];  const float* sa_bo = (const float*)d_in[9];
  const float* sa_lng = (const float*)d_in[10]; const float* sa_lnb = (const float*)d_in[11];
  const float* ca_wq = (const float*)d_in[12]; const float* ca_bq = (const float*)d_in[13];
  const float* ca_wk = (const float*)d_in[14]; const float* ca_bk = (const float*)d_in[15];
  const float* ca_wv = (const float*)d_in[16]; const float* ca_bv = (const float*)d_in[17];
  const float* ca_wo = (const float*)d_in[18]; const float* ca_bo = (const float*)d_in[19];
  const float* ca_lng = (const float*)d_in[20]; const float* ca_lnb = (const float*)d_in[21];
  const float* ff_w1 = (const float*)d_in[22]; const float* ff_b1 = (const float*)d_in[23];
  const float* ff_w2 = (const float*)d_in[24]; const float* ff_b2 = (const float*)d_in[25];
  const float* ff_lng = (const float*)d_in[26]; const float* ff_lnb = (const float*)d_in[27];

  char* ws = (char*)d_ws;
  size_t off = 0;
  auto alloc = [&](size_t bytes){ char* p = ws + off; off += (bytes + 255) & ~(size_t)255; return p; };

  unsigned short* wT[8];
  for (int i = 0; i < 8; i++) wT[i] = (unsigned short*)alloc(4096ULL*512*2);
  unsigned short* w1T  = (unsigned short*)alloc(1024ULL*512*2);
  unsigned short* w2T  = (unsigned short*)alloc(512ULL*1024*2);
  unsigned short* xbf  = (unsigned short*)alloc(4096ULL*512*2);
  unsigned short* inbf = (unsigned short*)alloc(4096ULL*512*2);
  unsigned short* qb   = (unsigned short*)alloc(4096ULL*4096*2);   // also FFN hidden
  unsigned short* kb   = (unsigned short*)alloc(4096ULL*4096*2);   // also attn-out
  unsigned short* vT   = (unsigned short*)alloc(64ULL*512*512*2);
  float*          sc   = (float*)alloc(64ULL*512*512*4);           // 64 MB multi-use
  float*          xcur = (float*)alloc(4096ULL*512*4);

  // sc region timeline: vb (V-proj) -> transpose_v -> f32 scores -> bf16
  // probs in-place -> PV -> 8 bf16 split-K partial slices -> ln_rows.
  unsigned short* vb   = (unsigned short*)sc;
  unsigned short* part = (unsigned short*)sc;
  const size_t PART_STRIDE = 2097152;   // ushorts per slice (4096*512)

  // ---- prologue (merged) ----
  Cast2 c2{{out_seq, in_seq}, {xbf, inbf}};
  cast_bf16_k2<<<dim3(2048,2), 256, 0, stream>>>(c2, 4096*512);

  TC8 tqkv{{sa_wq, sa_wk, sa_wv, ca_wq, ca_wk, ca_wv, nullptr, nullptr},
           {wT[0], wT[1], wT[2], wT[4], wT[5], wT[6], nullptr, nullptr}};
  transpose_cast8<<<dim3(128,16,6), 256, 0, stream>>>(tqkv, 512, 4096);
  TC8 two{{sa_wo, ca_wo, nullptr,nullptr,nullptr,nullptr,nullptr,nullptr},
          {wT[3], wT[7], nullptr,nullptr,nullptr,nullptr,nullptr,nullptr}};
  transpose_cast8<<<dim3(16,128,2), 256, 0, stream>>>(two, 4096, 512);
  TC8 tw1{{ff_w1, nullptr,nullptr,nullptr,nullptr,nullptr,nullptr,nullptr},
          {w1T, nullptr,nullptr,nullptr,nullptr,nullptr,nullptr,nullptr}};
  transpose_cast8<<<dim3(32,16,1), 256, 0, stream>>>(tw1, 512, 1024);
  TC8 tw2{{ff_w2, nullptr,nullptr,nullptr,nullptr,nullptr,nullptr,nullptr},
          {w2T, nullptr,nullptr,nullptr,nullptr,nullptr,nullptr,nullptr}};
  transpose_cast8<<<dim3(16,32,1), 256, 0, stream>>>(tw2, 1024, 512);

  #define G256(MODE, CSK, Apt, Bpt, Cpt, BIAS, M, N, K, LDA, LDB, LDC, Z, aH, aB, bH, bB, cH, cB) \
    gemm256<MODE, CSK><<<dim3((N)/256,(M)/256,(Z)), 512, 0, stream>>>( \
      (const unsigned short*)(Apt), (const unsigned short*)(Bpt), (void*)(Cpt), BIAS, \
      M, N, K, LDA, LDB, LDC, aH, aB, bH, bB, cH, cB)

  // ---- self-attention (causal) ----
  Proj3 saP{{xbf, xbf, xbf}, {wT[0], wT[1], wT[2]}, {qb, kb, vb}, {sa_bq, sa_bk, sa_bv}};
  qkv256<<<dim3(16,16,3), 512, 0, stream>>>(saP);
  transpose_v<<<dim3(16,16,64), 256, 0, stream>>>(vb, vT);
  G256(0, 1, qb, kb, sc, nullptr, 512, 512, 512, 4096, 4096, 512, 64,
       512, 2097152, 512, 2097152, 262144, 2097152);
  softmax_rows<1><<<8192, 256, 0, stream>>>(sc);
  G256(1, 2, sc, vT, kb, nullptr, 512, 512, 512, 1024, 512, 4096, 64,
       524288, 4194304, 262144, 2097152, 512, 2097152);
  G256(1, 0, kb, wT[3], part, nullptr, 4096, 512, 512, 4096, 4096, 512, 8,
       512, 0, 512, 0, PART_STRIDE, 0);
  ln_rows<1, 8, 1><<<1024, 256, 0, stream>>>(out_seq, part, PART_STRIDE,
                                             sa_bo, sa_lng, sa_lnb, xcur, xbf);

  // ---- cross-attention ----
  Proj3 caP{{xbf, inbf, inbf}, {wT[4], wT[5], wT[6]}, {qb, kb, vb}, {ca_bq, ca_bk, ca_bv}};
  qkv256<<<dim3(16,16,3), 512, 0, stream>>>(caP);
  transpose_v<<<dim3(16,16,64), 256, 0, stream>>>(vb, vT);
  G256(0, 0, qb, kb, sc, nullptr, 512, 512, 512, 4096, 4096, 512, 64,
       512, 2097152, 512, 2097152, 262144, 2097152);
  softmax_rows<0><<<8192, 256, 0, stream>>>(sc);
  G256(1, 0, sc, vT, kb, nullptr, 512, 512, 512, 1024, 512, 4096, 64,
       524288, 4194304, 262144, 2097152, 512, 2097152);
  G256(1, 0, kb, wT[7], part, nullptr, 4096, 512, 512, 4096, 4096, 512, 8,
       512, 0, 512, 0, PART_STRIDE, 0);
  ln_rows<1, 8, 1><<<1024, 256, 0, stream>>>(xcur, part, PART_STRIDE,
                                             ca_bo, ca_lng, ca_lnb, xcur, xbf);

  // ---- FFN ----
  gemm_bt<2><<<dim3(8,32,1), 256, 0, stream>>>(
      xbf, w1T, (void*)qb, ff_b1, 4096, 1024, 512, 512, 512, 1024);
  G256(1, 0, qb, w2T, part, nullptr, 4096, 512, 128, 1024, 1024, 512, 8,
       128, 0, 128, 0, PART_STRIDE, 0);
  ln_rows<0, 8, 1><<<1024, 256, 0, stream>>>(xcur, part, PART_STRIDE,
                                             ff_b2, ff_lng, ff_lnb, (float*)d_out, nullptr);

  #undef G256
}